// Round 5
// baseline (1460.904 us; speedup 1.0000x reference)
//
#include <hip/hip_runtime.h>
#include <stdint.h>

#define B_ 8
#define L_ 2048
#define D_ 1024
#define Z_ 128
#define H_ 2048
#define NE_ 16
#define G_ 32
#define MAXPOS_ 2048
#define NMX_ 4224   // D + Z + H + D (u | z | r | hx) = 33 * 128 exactly
#define EPS_ 1e-5f
#define PC_ 2.0f
#define NTILE_ 16            // L/128 q-tiles
#define NPACK_ 136           // 16*17/2 packed causal tiles
#define TILE_ELEMS_ 16384    // 128*128

typedef short bf16x8 __attribute__((ext_vector_type(8)));
typedef float f32x4 __attribute__((ext_vector_type(4)));

__device__ __forceinline__ float bf2f(uint16_t u) {
  union { uint32_t u; float f; } v; v.u = ((uint32_t)u) << 16; return v.f;
}
__device__ __forceinline__ uint16_t f2bf(float f) {
  union { float f; uint32_t u; } v; v.f = f;
  uint32_t r = (v.u + 0x7FFFu + ((v.u >> 16) & 1u)) >> 16;
  return (uint16_t)r;
}
__device__ __forceinline__ float sigmoidf_(float x) { return 1.f / (1.f + __expf(-x)); }
__device__ __forceinline__ float siluf_(float x) { return x / (1.f + __expf(-x)); }

__device__ __forceinline__ float waveRedSum(float v) {
  #pragma unroll
  for (int m = 32; m; m >>= 1) v += __shfl_xor(v, m, 64);
  return v;
}

// async global->LDS, 16 bytes per lane; lds dst must be waveBase + lane*16
__device__ __forceinline__ void gl2lds(const uint16_t* g, uint16_t* l) {
  __builtin_amdgcn_global_load_lds(
      (const __attribute__((address_space(1))) void*)g,
      (__attribute__((address_space(3))) void*)l, 16, 0, 0);
}

// ---------------- fallback when workspace too small ----------------
__global__ __launch_bounds__(256) void k_fallback(float* __restrict__ out, int n, float wsmb) {
  for (int i = blockIdx.x * 256 + threadIdx.x; i < n; i += gridDim.x * 256)
    out[i] = (i == 0) ? wsmb : 0.f;
}

// ---------------- fp32 -> bf16 conversion (weights) ----------------
__global__ __launch_bounds__(256) void k_f2bf(const float* __restrict__ src,
                                              uint16_t* __restrict__ dst, int n) {
  for (int i = blockIdx.x * 256 + threadIdx.x; i < n; i += gridDim.x * 256)
    dst[i] = f2bf(src[i]);
}

// ---------------- TimestepNorm, parallel 3-phase ----------------
__global__ __launch_bounds__(256) void k_tnsum(const float* __restrict__ x,
                                               float* __restrict__ s1g,
                                               float* __restrict__ s2g) {
  const int bg = blockIdx.x;
  const int b = bg / G_, g = bg % G_;
  const int tid = threadIdx.x;
  const int j = tid & 31;
  const int lsub = tid >> 5;
  #pragma unroll
  for (int i = 0; i < 16; ++i) {
    const int l = blockIdx.y * 128 + i * 8 + lsub;
    float v = x[((size_t)(b * L_ + l)) * D_ + g * 32 + j];
    float a = v, sq = v * v;
    #pragma unroll
    for (int m = 1; m <= 16; m <<= 1) { a += __shfl_xor(a, m, 64); sq += __shfl_xor(sq, m, 64); }
    if (j == 0) { s1g[(size_t)bg * L_ + l] = a; s2g[(size_t)bg * L_ + l] = sq; }
  }
}

__global__ __launch_bounds__(64) void k_tnscan(float* __restrict__ s1g,
                                               float* __restrict__ s2g) {
  const int bg = blockIdx.x;
  const int lane = threadIdx.x;
  #pragma unroll
  for (int pass = 0; pass < 2; ++pass) {
    float* gp = (pass ? s2g : s1g) + (size_t)bg * L_;
    float loc[32];
    const int b0 = lane * 32;
    float tot = 0.f;
    #pragma unroll
    for (int t = 0; t < 32; ++t) { loc[t] = gp[b0 + t]; tot += loc[t]; }
    float incl = tot;
    #pragma unroll
    for (int off = 1; off < 64; off <<= 1) {
      float nv = __shfl_up(incl, off, 64);
      if (lane >= off) incl += nv;
    }
    float run = incl - tot;
    #pragma unroll
    for (int t = 0; t < 32; ++t) { run += loc[t]; gp[b0 + t] = run; }
  }
}

__global__ __launch_bounds__(256) void k_tnnorm(const float* __restrict__ x,
                                                const float* __restrict__ s1g,
                                                const float* __restrict__ s2g,
                                                const float* __restrict__ pm,
                                                const float* __restrict__ plv,
                                                const float* __restrict__ w,
                                                const float* __restrict__ bias,
                                                uint16_t* __restrict__ xn) {
  const int bg = blockIdx.x;
  const int b = bg / G_, g = bg % G_;
  const int tid = threadIdx.x;
  const int j = tid & 31;
  const int lsub = tid >> 5;
  const float pmv = pm[g];
  const float pvv = __expf(plv[g]);
  const float wj = w[g * 32 + j];
  const float bj = bias[g * 32 + j];
  const float pterm = PC_ * (pvv + pmv * pmv);
  #pragma unroll
  for (int i = 0; i < 16; ++i) {
    const int l = blockIdx.y * 128 + i * 8 + lsub;
    const size_t idx = ((size_t)(b * L_ + l)) * D_ + g * 32 + j;
    const float v = x[idx];
    const float cnt = PC_ + 32.f * (float)(l + 1);
    const float mean = (PC_ * pmv + s1g[(size_t)bg * L_ + l]) / cnt;
    const float var = (pterm + s2g[(size_t)bg * L_ + l]) / cnt - mean * mean;
    xn[idx] = f2bf((v - mean) * rsqrtf(var + EPS_) * wj + bj);
  }
}

// ---------------- generic 32x32-tiled transpose, batched over z ----------------
template <typename T>
__global__ __launch_bounds__(256) void k_transpose(const T* __restrict__ src,
                                                   T* __restrict__ dst, int R, int C) {
  __shared__ T tile[32][33];
  const size_t batch = (size_t)R * C * blockIdx.z;
  const int c0 = blockIdx.x * 32, r0 = blockIdx.y * 32;
  const int tx = threadIdx.x & 31, ty = threadIdx.x >> 5;
  #pragma unroll
  for (int k = 0; k < 4; ++k) {
    int r = ty + k * 8;
    tile[r][tx] = src[batch + (size_t)(r0 + r) * C + c0 + tx];
  }
  __syncthreads();
  #pragma unroll
  for (int k = 0; k < 4; ++k) {
    int r = ty + k * 8;
    dst[batch + (size_t)(c0 + r) * R + r0 + tx] = tile[tx][r];
  }
}

// ---------------- MultiHeadEMA via chunked linear recurrence ----------------
__global__ __launch_bounds__(64) void k_ema(const uint16_t* __restrict__ xnT,
                                            const float* __restrict__ delta,
                                            const float* __restrict__ alpha,
                                            const float* __restrict__ beta,
                                            const float* __restrict__ gamma,
                                            const float* __restrict__ omega,
                                            float* __restrict__ mxT) {
  __shared__ float hst[64 * NE_];
  const int bd = blockIdx.x;
  const int d = bd & (D_ - 1);
  const int c = threadIdx.x;

  float q[NE_], pb[NE_], gs[NE_];
  #pragma unroll
  for (int n = 0; n < NE_; ++n) {
    float p = sigmoidf_(delta[d * NE_ + n]);
    float a = sigmoidf_(alpha[d * NE_ + n]);
    q[n] = 1.f - p * a;
    pb[n] = p * beta[d * NE_ + n];
    gs[n] = gamma[d * NE_ + n] * 0.25f;
  }

  const uint16_t* xp = xnT + (size_t)bd * L_ + c * 32;
  bf16x8 xin[4];
  #pragma unroll
  for (int s = 0; s < 4; ++s) xin[s] = *(const bf16x8*)(xp + s * 8);

  float h[NE_];
  #pragma unroll
  for (int n = 0; n < NE_; ++n) h[n] = 0.f;

  #pragma unroll
  for (int k = 0; k < 32; ++k) {
    float xv = bf2f((uint16_t)xin[k >> 3][k & 7]);
    #pragma unroll
    for (int n = 0; n < NE_; ++n) h[n] = fmaf(q[n], h[n], pb[n] * xv);
  }
  #pragma unroll
  for (int n = 0; n < NE_; ++n) hst[c * NE_ + n] = h[n];
  __syncthreads();

  if (c < NE_) {
    float qq = q[c];
    float q32 = qq * qq; q32 *= q32; q32 *= q32; q32 *= q32; q32 *= q32;  // q^32
    float hi = 0.f;
    for (int cc = 0; cc < 64; ++cc) {
      float cur = hst[cc * NE_ + c];
      hst[cc * NE_ + c] = hi;
      hi = fmaf(q32, hi, cur);
    }
  }
  __syncthreads();

  #pragma unroll
  for (int n = 0; n < NE_; ++n) h[n] = hst[c * NE_ + n];
  const float om = omega[d];
  float* op = mxT + (size_t)bd * L_ + c * 32;
  f32x4 ov;
  #pragma unroll
  for (int k = 0; k < 32; ++k) {
    float xv = bf2f((uint16_t)xin[k >> 3][k & 7]);
    float accv = 0.f;
    #pragma unroll
    for (int n = 0; n < NE_; ++n) {
      h[n] = fmaf(q[n], h[n], pb[n] * xv);
      accv = fmaf(gs[n], h[n], accv);
    }
    ov[k & 3] = accv + om * xv;
    if ((k & 3) == 3) *(f32x4*)(op + (k & ~3)) = ov;
  }
}

// ---------------- RMS norm over D ----------------
__global__ __launch_bounds__(256) void k_rms(const float* __restrict__ mx,
                                             const float* __restrict__ w,
                                             uint16_t* __restrict__ mxn) {
  __shared__ float red[4];
  const size_t row = blockIdx.x;
  const int tid = threadIdx.x;
  float ss = 0.f;
  #pragma unroll
  for (int i = 0; i < 4; ++i) {
    float v = mx[row * D_ + tid + i * 256];
    ss += v * v;
  }
  ss = waveRedSum(ss);
  if ((tid & 63) == 0) red[tid >> 6] = ss;
  __syncthreads();
  ss = red[0] + red[1] + red[2] + red[3];
  const float scale = rsqrtf(ss * (1.f / D_) + EPS_);
  #pragma unroll
  for (int i = 0; i < 4; ++i) {
    int dcol = tid + i * 256;
    mxn[row * D_ + dcol] = f2bf(mx[row * D_ + dcol] * scale * w[dcol]);
  }
}

// ---------------- q/k prep from z ----------------
__global__ __launch_bounds__(256) void k_qkprep(const float* __restrict__ z,
                                                const float* __restrict__ qg,
                                                const float* __restrict__ qb,
                                                uint16_t* __restrict__ q,
                                                uint16_t* __restrict__ k, int n) {
  for (int i = blockIdx.x * 256 + threadIdx.x; i < n; i += gridDim.x * 256) {
    int zc = i & (Z_ - 1);
    float v = z[i];
    q[i] = f2bf((v * qg[zc] + qb[zc]) * 0.08838834764831845f);
    k[i] = f2bf(v * qg[Z_ + zc] + qb[Z_ + zc]);
  }
}

// ==================================================================
// 128x128-tile, BK=32, 4-wave, 2-phase prefetch GEMM, ~5 blocks/CU.
//
// Round-5 rationale: round-4's BK=64 dbuf = 64 KiB LDS -> hard 2
// blocks/CU (160/64); per-tile vmcnt(0) drains (~500-700 cy) only
// partially hidden.  BK=32 dbuf = 32 KiB -> 5 blocks/CU (LDS exactly
// 160 KiB), launch_bounds(256,5) caps VGPR at 102 (build uses ~88).
// 5 independent blocks x ~185 cy/tile of issue work covers the ~900 cy
// load latency (m114/m97 mechanism; m132 showed 64 KiB/2-block = 508 TF
// vs 16 KiB/3-block = 874 at this tile size).
//
// Swizzle for [128][32] tiles (64 B rows, bank-group = 4*(row&1)+g):
// phys granule = logical ^ ((row>>1)&3) -> 2-way (free).  Staging keeps
// LDS dest linear (gl2lds) and pre-swizzles the GLOBAL source column.
//
// C = A(MxK) @ B(NxK)^T, fused epilogues:
//  MODE 0: V     out = silu(acc + bv[col])               -> bf16 v
//  MODE 1: BASE  acc + bmx[col], split u/z/r/hx (N=4224=33*128)
//  MODE 4: WH    g=silu(acc+hx); out = x + u*(g-x)        -> f32 d_out
// ==================================================================

template <int MODE>
__global__ __launch_bounds__(256, 5) void k_gemm128(
    const uint16_t* __restrict__ A, const uint16_t* __restrict__ Bm,
    int N, int K,
    const float* __restrict__ bias,
    float* __restrict__ outf, uint16_t* __restrict__ outb,
    uint16_t* __restrict__ ubuf, float* __restrict__ zbuf,
    uint16_t* __restrict__ rbuf, float* __restrict__ hxbuf,
    const float* __restrict__ x0) {
  __shared__ uint16_t sm[16384];  // 32 KiB: buf c at c*8192; A +0, B +4096
  const int t = threadIdx.x;
  const int lane = t & 63, wave = t >> 6;
  const int quad = lane >> 4, r16 = lane & 15;
  const int wm = wave >> 1, wn = wave & 1;
  const int bm = blockIdx.x * 128;
  const int bn = blockIdx.y * 128;

  f32x4 acc[4][4];
  const f32x4 zf = {0.f, 0.f, 0.f, 0.f};
  #pragma unroll
  for (int i = 0; i < 4; ++i)
    #pragma unroll
    for (int j = 0; j < 4; ++j) acc[i][j] = zf;

  // staging: thread t -> rows {t>>2, 64+(t>>2)}, phys granule t&3;
  // LDS dest linear; global col pre-swizzled: logical = (t&3)^((t>>3)&3)
  const int sgz = (((t & 3) ^ ((t >> 3) & 3)) << 3);
  const uint16_t* gA = A + (size_t)(bm + (t >> 2)) * K + sgz;
  const uint16_t* gB = Bm + (size_t)(bn + (t >> 2)) * K + sgz;
  const size_t qstep = (size_t)64 * K;
  uint16_t* lA = sm + t * 8;
  uint16_t* lB = sm + 4096 + t * 8;

  // reads: row*32 + ((quad ^ ((row>>1)&3))<<3); row>>1 mod 4 = r16>>1 mod 4
  const int ga = ((quad ^ ((r16 >> 1) & 3)) << 3);
  const int aOff = (wm * 64 + r16) * 32 + ga;
  const int bOff = 4096 + (wn * 64 + r16) * 32 + ga;

#define STAGE(c, kb) do {                                                     \
    gl2lds(gA + (kb), lA + (c) * 8192);                                       \
    gl2lds(gA + qstep + (kb), lA + (c) * 8192 + 2048);                        \
    gl2lds(gB + (kb), lB + (c) * 8192);                                       \
    gl2lds(gB + qstep + (kb), lB + (c) * 8192 + 2048);                        \
  } while (0)

  const int NT = K >> 5;

  STAGE(0, 0);
  __syncthreads();  // vmcnt(0) drain + barrier

  bf16x8 af[4], bfr[4];
  for (int tt = 0; tt < NT; ++tt) {
    const int c = tt & 1;
    const int co = c * 8192;
    if (tt + 1 < NT) STAGE(c ^ 1, (tt + 1) * 32);  // prefetch next tile
    #pragma unroll
    for (int j = 0; j < 4; ++j)
      bfr[j] = *(const bf16x8*)&sm[co + bOff + j * 512];
    #pragma unroll
    for (int i = 0; i < 4; ++i)
      af[i] = *(const bf16x8*)&sm[co + aOff + i * 512];
    #pragma unroll
    for (int i = 0; i < 4; ++i)
      #pragma unroll
      for (int j = 0; j < 4; ++j)
        acc[i][j] = __builtin_amdgcn_mfma_f32_16x16x32_bf16(
            af[i], bfr[j], acc[i][j], 0, 0, 0);
    __syncthreads();  // single vmcnt(0)+barrier per K-tile
  }
#undef STAGE

  // ---- epilogue ----
  #pragma unroll
  for (int i = 0; i < 4; ++i) {
    #pragma unroll
    for (int j = 0; j < 4; ++j) {
      #pragma unroll
      for (int r = 0; r < 4; ++r) {
        const int row = bm + wm * 64 + i * 16 + quad * 4 + r;
        const int col = bn + wn * 64 + j * 16 + r16;
        float val = acc[i][j][r];
        if (MODE == 0) {
          outb[(size_t)row * N + col] = f2bf(siluf_(val + bias[col]));
        } else if (MODE == 1) {
          val += bias[col];
          if (col < D_)                 ubuf[(size_t)row * D_ + col] = f2bf(sigmoidf_(val));
          else if (col < D_ + Z_)       zbuf[(size_t)row * Z_ + (col - D_)] = siluf_(val);
          else if (col < D_ + Z_ + H_)  rbuf[(size_t)row * H_ + (col - D_ - Z_)] = f2bf(siluf_(val));
          else                          hxbuf[(size_t)row * D_ + (col - D_ - Z_ - H_)] = val;
        } else {
          const size_t idx = (size_t)row * N + col;
          float g = siluf_(val + hxbuf[idx]);   // read hx (d_out) ...
          float xv = x0[idx];
          outf[idx] = xv + bf2f(ubuf[idx]) * (g - xv);  // ... then write same addr
        }
      }
    }
  }
}

// ---- fused QK^T + rel_bias + causal softmax -> packed-triangular P (bf16) ----
// Ks rows are 128 elems (256 B): granule XOR-swizzle phys = logical^(row&7);
// staging pre-swizzles the global source column, LDS dest stays linear.
__global__ __launch_bounds__(256) void k_qksm(
    const uint16_t* __restrict__ qg, const uint16_t* __restrict__ kg,
    const float* __restrict__ relb, uint16_t* __restrict__ Pp) {
  __shared__ uint16_t Ks[128 * 128];
  __shared__ float relwin[256];
  const int qt = blockIdx.x;
  const int bl = blockIdx.y;
  const int tid = threadIdx.x;
  const int w = tid >> 6, lane = tid & 63;
  const int quad = lane >> 4, r16 = lane & 15;
  const uint16_t* qb_b = qg + (size_t)bl * L_ * Z_;
  const uint16_t* kb_b = kg + (size_t)bl * L_ * Z_;
  uint16_t* P_b = Pp + (size_t)bl * NPACK_ * TILE_ELEMS_;

  const int ksg = (tid >> 4) * 128 + (((tid & 15) ^ ((tid >> 4) & 7)) << 3);
  const int kg7 = r16 & 7;

  bf16x8 aq[2][4];
  #pragma unroll
  for (int i = 0; i < 2; ++i)
    #pragma unroll
    for (int s = 0; s < 4; ++s)
      aq[i][s] = *(const bf16x8*)&qb_b[(size_t)(qt * 128 + w * 32 + i * 16 + r16) * Z_ +
                                       s * 32 + quad * 8];

  float m8[8], l8[8];
  #pragma unroll
  for (int t = 0; t < 8; ++t) { m8[t] = -3.4e38f; l8[t] = 0.f; }

  const f32x4 zf = {0.f, 0.f, 0.f, 0.f};

  // ---- phase 1: stats ----
  for (int kt = 0; kt <= qt; ++kt) {
    __syncthreads();
    const uint16_t* src = kb_b + (size_t)kt * 128 * Z_;
    #pragma unroll
    for (int s2 = 0; s2 < 8; ++s2)
      gl2lds(src + s2 * 2048 + ksg, Ks + s2 * 2048 + tid * 8);
    if (tid < 255) relwin[tid] = relb[2047 + (kt - qt) * 128 - 127 + tid];
    __syncthreads();
    #pragma unroll
    for (int j = 0; j < 8; ++j) {
      f32x4 a0 = zf, a1 = zf;
      #pragma unroll
      for (int s = 0; s < 4; ++s) {
        bf16x8 bk = *(const bf16x8*)&Ks[(j * 16 + r16) * 128 +
                                        (((s * 4 + quad) ^ kg7) << 3)];
        a0 = __builtin_amdgcn_mfma_f32_16x16x32_bf16(aq[0][s], bk, a0, 0, 0, 0);
        a1 = __builtin_amdgcn_mfma_f32_16x16x32_bf16(aq[1][s], bk, a1, 0, 0, 0);
      }
      #pragma unroll
      for (int i = 0; i < 2; ++i) {
        const f32x4 av = i ? a1 : a0;
        #pragma unroll
        for (int r = 0; r < 4; ++r) {
          const int rloc = w * 32 + i * 16 + quad * 4 + r;
          const int cloc = j * 16 + r16;
          if (kt < qt || cloc <= rloc) {
            const float v = av[r] + relwin[cloc - rloc + 127];
            const int t = i * 4 + r;
            const float mn = fmaxf(m8[t], v);
            l8[t] = l8[t] * __expf(m8[t] - mn) + __expf(v - mn);
            m8[t] = mn;
          }
        }
      }
    }
  }

  #pragma unroll
  for (int t = 0; t < 8; ++t) {
    #pragma unroll
    for (int msk = 1; msk <= 8; msk <<= 1) {
      const float mo = __shfl_xor(m8[t], msk, 64);
      const float lo = __shfl_xor(l8[t], msk, 64);
      const float mn = fmaxf(m8[t], mo);
      l8[t] = l8[t] * __expf(m8[t] - mn) + lo * __expf(mo - mn);
      m8[t] = mn;
    }
    l8[t] = 1.f / l8[t];
  }

  // ---- phase 2: recompute, normalize, write packed P ----
  for (int kt = 0; kt <= qt; ++kt) {
    __syncthreads();
    const uint16_t* src = kb_b + (size_t)kt * 128 * Z_;
    #pragma unroll
    for (int s2 = 0; s2 < 8; ++s2)
      gl2lds(src + s2 * 2048 + ksg, Ks + s2 * 2048 + tid * 8);
    if (tid < 255) relwin[tid] = relb[2047 + (kt - qt) * 128 - 127 + tid];
    __syncthreads();
    uint16_t* Pt = P_b + (size_t)(qt * (qt + 1) / 2 + kt) * TILE_ELEMS_;
    #pragma unroll
    for (int j = 0; j < 8; ++j) {
      f32x4 a0 = zf, a1 = zf;
      #pragma unroll
      for (int s = 0; s < 4; ++s) {
        bf16x8 bk = *(const bf16x8*)&Ks[(j * 16 + r16) * 128 +
                                        (((s * 4 + quad) ^ kg7) << 3)];
        a0 = __builtin_amdgcn_mfma_f32_16x16x32_bf16(aq[0][s], bk, a0, 0, 0, 0);
        a1 = __builtin_amdgcn_mfma_f32_16x16x32_bf16(aq[1][s], bk, a1, 0, 0, 0);
      }
      #pragma unroll
      for (int i = 0; i < 2; ++i) {
        const f32x4 av = i ? a1 : a0;
        #pragma unroll
        for (int r = 0; r < 4; ++r) {
          const int rloc = w * 32 + i * 16 + quad * 4 + r;
          const int cloc = j * 16 + r16;
          const int t = i * 4 + r;
          float p = 0.f;
          if (kt < qt || cloc <= rloc) {
            const float v = av[r] + relwin[cloc - rloc + 127];
            p = __expf(v - m8[t]) * l8[t];
          }
          Pt[rloc * 128 + cloc] = f2bf(p);
        }
      }
    }
  }
}

// ---- PV GEMM: hr = (P @ V) * r, packed-triangular P, in-place over r ----
// BK=32 double-buffered prefetch (1 barrier/step), 32 KiB LDS, 5 blocks/CU.
// Swizzle: phys granule = logical ^ ((row>>1)&3) (2-way free on [*][32]).
// Grid reversed so heavy (large qt) blocks launch first.
__global__ __launch_bounds__(256, 5) void k_pv(
    const uint16_t* __restrict__ Pp, const uint16_t* __restrict__ vT,
    uint16_t* __restrict__ rh) {
  __shared__ uint16_t sm[16384];  // 32 KiB: buf c at c*8192; A +0, B +4096
  const int qt = NTILE_ - 1 - blockIdx.x;   // heavy blocks first
  const int bn = blockIdx.y * 128;
  const int bl = blockIdx.z;
  const uint16_t* Pq = Pp + (size_t)bl * NPACK_ * TILE_ELEMS_ +
                       (size_t)(qt * (qt + 1) / 2) * TILE_ELEMS_;
  const uint16_t* v_b = vT + (size_t)bl * H_ * L_;
  uint16_t* rh_b = rh + (size_t)bl * L_ * H_;

  const int tid = threadIdx.x;
  const int wave = tid >> 6, lane = tid & 63;
  const int quad = lane >> 4, r16 = lane & 15;
  const int wm = wave >> 1, wn = wave & 1;
  const int rowW = wm * 64, colW = wn * 64;

  f32x4 acc[4][4];
  const f32x4 zf = {0.f, 0.f, 0.f, 0.f};
  #pragma unroll
  for (int i = 0; i < 4; ++i)
    #pragma unroll
    for (int j = 0; j < 4; ++j) acc[i][j] = zf;

  const int rA = tid >> 2;
  // staging: phys granule tid&3 -> logical (tid&3)^((rA>>1)&3)
  const int sg = (((tid & 3) ^ ((tid >> 3) & 3)) << 3);
  // reads: phys granule = quad ^ ((row>>1)&3)
  const int gpv = ((quad ^ ((r16 >> 1) & 3)) << 3);

#define PVSTAGE(c, s) do {                                                    \
    const int kt_ = (s) >> 2, ks_ = (s) & 3;                                  \
    const uint16_t* At_ = Pq + (size_t)kt_ * TILE_ELEMS_ + ks_ * 32 + sg;     \
    const uint16_t* Bt_ = v_b + (size_t)(bn + rA) * L_ + kt_ * 128 +          \
                          ks_ * 32 + sg;                                      \
    gl2lds(At_ + rA * 128, sm + (c) * 8192 + tid * 8);                        \
    gl2lds(At_ + (rA + 64) * 128, sm + (c) * 8192 + 2048 + tid * 8);          \
    gl2lds(Bt_, sm + (c) * 8192 + 4096 + tid * 8);                            \
    gl2lds(Bt_ + (size_t)64 * L_, sm + (c) * 8192 + 6144 + tid * 8);          \
  } while (0)

  const int S = 4 * (qt + 1);

  PVSTAGE(0, 0);
  __syncthreads();

  bf16x8 af[4], bfr[4];
  for (int s = 0; s < S; ++s) {
    const int c = s & 1;
    const int co = c * 8192;
    if (s + 1 < S) PVSTAGE(c ^ 1, s + 1);
    #pragma unroll
    for (int j = 0; j < 4; ++j)
      bfr[j] = *(const bf16x8*)&sm[co + 4096 + (colW + j * 16 + r16) * 32 + gpv];
    #pragma unroll
    for (int i = 0; i < 4; ++i)
      af[i] = *(const bf16x8*)&sm[co + (rowW + i * 16 + r16) * 32 + gpv];
    #pragma unroll
    for (int i = 0; i < 4; ++i)
      #pragma unroll
      for (int j = 0; j < 4; ++j)
        acc[i][j] = __builtin_amdgcn_mfma_f32_16x16x32_bf16(af[i], bfr[j], acc[i][j], 0, 0, 0);
    __syncthreads();
  }
#undef PVSTAGE

  #pragma unroll
  for (int i = 0; i < 4; ++i) {
    #pragma unroll
    for (int j = 0; j < 4; ++j) {
      #pragma unroll
      for (int r = 0; r < 4; ++r) {
        const int row = qt * 128 + rowW + i * 16 + quad * 4 + r;
        const int col = bn + colW + j * 16 + r16;
        const size_t idx = (size_t)row * H_ + col;
        const float rv = bf2f(rh_b[idx]);
        rh_b[idx] = f2bf(acc[i][j][r] * rv);
      }
    }
  }
}

extern "C" void kernel_launch(void* const* d_in, const int* in_sizes, int n_in,
                              void* d_out, int out_size, void* d_ws, size_t ws_size,
                              hipStream_t stream) {
  (void)in_sizes; (void)n_in;
  const float* x         = (const float*)d_in[0];
  const float* prior_mean= (const float*)d_in[1];
  const float* prior_logv= (const float*)d_in[2];
  const float* tn_w      = (const float*)d_in[3];
  const float* tn_b      = (const float*)d_in[4];
  const float* delta     = (const float*)d_in[5];
  const float* alpha     = (const float*)d_in[6];
  const float* ema_beta  = (const float*)d_in[7];
  const float* ema_gamma = (const float*)d_in[8];
  const float* omega     = (const float*)d_in[9];
  const float* rms_w     = (const float*)d_in[10];
  const float* Wv        = (const float*)d_in[11];
  const float* bv        = (const float*)d_in[12];
  const float* Wmx       = (const float*)d_in[13];
  const float* bmx       = (const float*)d_in[14];
  const float* Wh        = (const float*)d_in[15];
  const float* qk_gamma  = (const float*)d_in[16];
  const float* qk_beta   = (const float*)d_in[17];
  const float* rel_bias  = (const float*)d_in[18];
  float* out = (float*)d_out;

  const int BL = B_ * L_;
  const size_t MB = 1024 * 1024;
  const size_t REQUIRED = 256 * MB;

  if (ws_size < REQUIRED) {
    k_fallback<<<dim3(4096), dim3(256), 0, stream>>>(out, out_size, (float)(ws_size / MB));
    return;
  }

  char* p = (char*)d_ws;
  // A [0,32): xn (bf16) -> ubuf (bf16)
  uint16_t* xn   = (uint16_t*)(p);
  uint16_t* ubuf = (uint16_t*)(p);
  // B [32,64): s1s2 (4MB, tnorm only) -> xnT -> mxn
  float*    s1g  = (float*)   (p + 32 * MB);
  float*    s2g  = (float*)   (p + 34 * MB);
  uint16_t* xnT  = (uint16_t*)(p + 32 * MB);
  uint16_t* mxn  = (uint16_t*)(p + 32 * MB);
  // C [64,128): vbuf -> mx (f32) -> rbuf/hr (in-place PV)
  uint16_t* vbuf = (uint16_t*)(p + 64 * MB);
  float*    mx   = (float*)   (p + 64 * MB);
  uint16_t* rbuf = (uint16_t*)(p + 64 * MB);
  // D [128,192): wv_b -> vT
  uint16_t* wv_b = (uint16_t*)(p + 128 * MB);
  uint16_t* vT   = (uint16_t*)(p + 128 * MB);
  // E [192,256): wmx_b(8.25) | z(8) | qb(4) | kb(4) | Ppack(35.65)
  uint16_t* wmx_b = (uint16_t*)(p + 192 * MB);
  uint16_t* wh_b  = (uint16_t*)(p + 192 * MB);
  float*    zb    = (float*)   (p + 201 * MB);
  uint16_t* qb    = (uint16_t*)(p + 209 * MB);
  uint16_t* kb2   = (uint16_t*)(p + 213 * MB);
  uint16_t* Ppack = (uint16_t*)(p + 217 * MB);
  // d_out doubles as: mxT f32 (EMA out) -> hx f32 (BASE out) -> out
  float* mxT = out;
  float* hx  = out;

  // 1. weights -> bf16
  k_f2bf<<<dim3(1024), dim3(256), 0, stream>>>(Wv, wv_b, H_ * D_);
  k_f2bf<<<dim3(2048), dim3(256), 0, stream>>>(Wmx, wmx_b, NMX_ * D_);
  // 2. timestep norm (3-phase parallel) -> xn
  k_tnsum<<<dim3(B_ * G_, 16), dim3(256), 0, stream>>>(x, s1g, s2g);
  k_tnscan<<<dim3(B_ * G_), dim3(64), 0, stream>>>(s1g, s2g);
  k_tnnorm<<<dim3(B_ * G_, 16), dim3(256), 0, stream>>>(
      x, s1g, s2g, prior_mean, prior_logv, tn_w, tn_b, xn);
  // 3. xn -> xnT (overwrites dead s1s2)
  k_transpose<uint16_t><<<dim3(D_ / 32, L_ / 32, B_), dim3(256), 0, stream>>>(xn, xnT, L_, D_);
  // 4. v = silu(xn @ Wv^T + bv) -> vbuf
  k_gemm128<0><<<dim3(BL / 128, H_ / 128), dim3(256), 0, stream>>>(
      xn, wv_b, H_, D_, bv, nullptr, vbuf,
      nullptr, nullptr, nullptr, nullptr, nullptr);
  // 5. v -> vT (overwrites dead wv_b)
  k_transpose<uint16_t><<<dim3(H_ / 32, L_ / 32, B_), dim3(256), 0, stream>>>(vbuf, vT, L_, H_);
  // 6. EMA: xnT -> mxT (d_out)
  k_ema<<<dim3(B_ * D_), dim3(64), 0, stream>>>(xnT, delta, alpha, ema_beta, ema_gamma, omega, mxT);
  // 7. mxT -> mx (overwrites dead vbuf)
  k_transpose<float><<<dim3(L_ / 32, D_ / 32, B_), dim3(256), 0, stream>>>(mxT, mx, D_, L_);
  // 8. RMS norm -> mxn (overwrites dead xnT)
  k_rms<<<dim3(BL), dim3(256), 0, stream>>>(mx, rms_w, mxn);
  // 9. BASE GEMM -> u(A), z(E), r(C), hx(d_out)
  k_gemm128<1><<<dim3(BL / 128, NMX_ / 128), dim3(256), 0, stream>>>(
      mxn, wmx_b, NMX_, D_, bmx, nullptr, nullptr,
      ubuf, zb, rbuf, hx, nullptr);
  // 10. q,k from z
  k_qkprep<<<dim3(1024), dim3(256), 0, stream>>>(zb, qk_gamma, qk_beta, qb, kb2, BL * Z_);
  // 11. fused QK+softmax -> packed P (all 8 batches, one dispatch)
  k_qksm<<<dim3(NTILE_, B_), dim3(256), 0, stream>>>(qb, kb2, rel_bias, Ppack);
  // 12. PV GEMM, hr = (P@V)*r in-place over rbuf (one dispatch)
  k_pv<<<dim3(NTILE_, H_ / 128, B_), dim3(256), 0, stream>>>(Ppack, vT, rbuf);
  // 13. Wh -> bf16 (over dead wmx_b)
  k_f2bf<<<dim3(1024), dim3(256), 0, stream>>>(Wh, wh_b, D_ * H_);
  // 14. final: g = silu(hx + hr@Wh^T); out = x + u*(g-x)
  k_gemm128<4><<<dim3(BL / 128, D_ / 128), dim3(256), 0, stream>>>(
      rbuf, wh_b, D_, H_, nullptr, out, nullptr,
      ubuf, nullptr, nullptr, hx, x);
}

// Round 6
// 1202.827 us; speedup vs baseline: 1.2146x; 1.2146x over previous
//
#include <hip/hip_runtime.h>
#include <stdint.h>

#define B_ 8
#define L_ 2048
#define D_ 1024
#define Z_ 128
#define H_ 2048
#define NE_ 16
#define G_ 32
#define MAXPOS_ 2048
#define NMX_ 4224   // D + Z + H + D (u | z | r | hx) = 33 * 128 exactly
#define EPS_ 1e-5f
#define PC_ 2.0f
#define NTILE_ 16            // L/128 q-tiles
#define NPACK_ 136           // 16*17/2 packed causal tiles
#define TILE_ELEMS_ 16384    // 128*128

typedef short bf16x8 __attribute__((ext_vector_type(8)));
typedef float f32x4 __attribute__((ext_vector_type(4)));

__device__ __forceinline__ float bf2f(uint16_t u) {
  union { uint32_t u; float f; } v; v.u = ((uint32_t)u) << 16; return v.f;
}
__device__ __forceinline__ uint16_t f2bf(float f) {
  union { float f; uint32_t u; } v; v.f = f;
  uint32_t r = (v.u + 0x7FFFu + ((v.u >> 16) & 1u)) >> 16;
  return (uint16_t)r;
}
__device__ __forceinline__ float sigmoidf_(float x) { return 1.f / (1.f + __expf(-x)); }
__device__ __forceinline__ float siluf_(float x) { return x / (1.f + __expf(-x)); }

__device__ __forceinline__ float waveRedSum(float v) {
  #pragma unroll
  for (int m = 32; m; m >>= 1) v += __shfl_xor(v, m, 64);
  return v;
}

// async global->LDS, 16 bytes per lane; lds dst must be waveBase + lane*16
__device__ __forceinline__ void gl2lds(const uint16_t* g, uint16_t* l) {
  __builtin_amdgcn_global_load_lds(
      (const __attribute__((address_space(1))) void*)g,
      (__attribute__((address_space(3))) void*)l, 16, 0, 0);
}

// ---------------- fallback when workspace too small ----------------
__global__ __launch_bounds__(256) void k_fallback(float* __restrict__ out, int n, float wsmb) {
  for (int i = blockIdx.x * 256 + threadIdx.x; i < n; i += gridDim.x * 256)
    out[i] = (i == 0) ? wsmb : 0.f;
}

// ---------------- fp32 -> bf16 conversion (weights) ----------------
__global__ __launch_bounds__(256) void k_f2bf(const float* __restrict__ src,
                                              uint16_t* __restrict__ dst, int n) {
  for (int i = blockIdx.x * 256 + threadIdx.x; i < n; i += gridDim.x * 256)
    dst[i] = f2bf(src[i]);
}

// ---------------- TimestepNorm, parallel 3-phase ----------------
__global__ __launch_bounds__(256) void k_tnsum(const float* __restrict__ x,
                                               float* __restrict__ s1g,
                                               float* __restrict__ s2g) {
  const int bg = blockIdx.x;
  const int b = bg / G_, g = bg % G_;
  const int tid = threadIdx.x;
  const int j = tid & 31;
  const int lsub = tid >> 5;
  #pragma unroll
  for (int i = 0; i < 16; ++i) {
    const int l = blockIdx.y * 128 + i * 8 + lsub;
    float v = x[((size_t)(b * L_ + l)) * D_ + g * 32 + j];
    float a = v, sq = v * v;
    #pragma unroll
    for (int m = 1; m <= 16; m <<= 1) { a += __shfl_xor(a, m, 64); sq += __shfl_xor(sq, m, 64); }
    if (j == 0) { s1g[(size_t)bg * L_ + l] = a; s2g[(size_t)bg * L_ + l] = sq; }
  }
}

__global__ __launch_bounds__(64) void k_tnscan(float* __restrict__ s1g,
                                               float* __restrict__ s2g) {
  const int bg = blockIdx.x;
  const int lane = threadIdx.x;
  #pragma unroll
  for (int pass = 0; pass < 2; ++pass) {
    float* gp = (pass ? s2g : s1g) + (size_t)bg * L_;
    float loc[32];
    const int b0 = lane * 32;
    float tot = 0.f;
    #pragma unroll
    for (int t = 0; t < 32; ++t) { loc[t] = gp[b0 + t]; tot += loc[t]; }
    float incl = tot;
    #pragma unroll
    for (int off = 1; off < 64; off <<= 1) {
      float nv = __shfl_up(incl, off, 64);
      if (lane >= off) incl += nv;
    }
    float run = incl - tot;
    #pragma unroll
    for (int t = 0; t < 32; ++t) { run += loc[t]; gp[b0 + t] = run; }
  }
}

__global__ __launch_bounds__(256) void k_tnnorm(const float* __restrict__ x,
                                                const float* __restrict__ s1g,
                                                const float* __restrict__ s2g,
                                                const float* __restrict__ pm,
                                                const float* __restrict__ plv,
                                                const float* __restrict__ w,
                                                const float* __restrict__ bias,
                                                uint16_t* __restrict__ xn) {
  const int bg = blockIdx.x;
  const int b = bg / G_, g = bg % G_;
  const int tid = threadIdx.x;
  const int j = tid & 31;
  const int lsub = tid >> 5;
  const float pmv = pm[g];
  const float pvv = __expf(plv[g]);
  const float wj = w[g * 32 + j];
  const float bj = bias[g * 32 + j];
  const float pterm = PC_ * (pvv + pmv * pmv);
  #pragma unroll
  for (int i = 0; i < 16; ++i) {
    const int l = blockIdx.y * 128 + i * 8 + lsub;
    const size_t idx = ((size_t)(b * L_ + l)) * D_ + g * 32 + j;
    const float v = x[idx];
    const float cnt = PC_ + 32.f * (float)(l + 1);
    const float mean = (PC_ * pmv + s1g[(size_t)bg * L_ + l]) / cnt;
    const float var = (pterm + s2g[(size_t)bg * L_ + l]) / cnt - mean * mean;
    xn[idx] = f2bf((v - mean) * rsqrtf(var + EPS_) * wj + bj);
  }
}

// ---------------- generic 32x32-tiled transpose, batched over z ----------------
template <typename T>
__global__ __launch_bounds__(256) void k_transpose(const T* __restrict__ src,
                                                   T* __restrict__ dst, int R, int C) {
  __shared__ T tile[32][33];
  const size_t batch = (size_t)R * C * blockIdx.z;
  const int c0 = blockIdx.x * 32, r0 = blockIdx.y * 32;
  const int tx = threadIdx.x & 31, ty = threadIdx.x >> 5;
  #pragma unroll
  for (int k = 0; k < 4; ++k) {
    int r = ty + k * 8;
    tile[r][tx] = src[batch + (size_t)(r0 + r) * C + c0 + tx];
  }
  __syncthreads();
  #pragma unroll
  for (int k = 0; k < 4; ++k) {
    int r = ty + k * 8;
    dst[batch + (size_t)(c0 + r) * R + r0 + tx] = tile[tx][r];
  }
}

// ---------------- MultiHeadEMA via chunked linear recurrence ----------------
__global__ __launch_bounds__(64) void k_ema(const uint16_t* __restrict__ xnT,
                                            const float* __restrict__ delta,
                                            const float* __restrict__ alpha,
                                            const float* __restrict__ beta,
                                            const float* __restrict__ gamma,
                                            const float* __restrict__ omega,
                                            float* __restrict__ mxT) {
  __shared__ float hst[64 * NE_];
  const int bd = blockIdx.x;
  const int d = bd & (D_ - 1);
  const int c = threadIdx.x;

  float q[NE_], pb[NE_], gs[NE_];
  #pragma unroll
  for (int n = 0; n < NE_; ++n) {
    float p = sigmoidf_(delta[d * NE_ + n]);
    float a = sigmoidf_(alpha[d * NE_ + n]);
    q[n] = 1.f - p * a;
    pb[n] = p * beta[d * NE_ + n];
    gs[n] = gamma[d * NE_ + n] * 0.25f;
  }

  const uint16_t* xp = xnT + (size_t)bd * L_ + c * 32;
  bf16x8 xin[4];
  #pragma unroll
  for (int s = 0; s < 4; ++s) xin[s] = *(const bf16x8*)(xp + s * 8);

  float h[NE_];
  #pragma unroll
  for (int n = 0; n < NE_; ++n) h[n] = 0.f;

  #pragma unroll
  for (int k = 0; k < 32; ++k) {
    float xv = bf2f((uint16_t)xin[k >> 3][k & 7]);
    #pragma unroll
    for (int n = 0; n < NE_; ++n) h[n] = fmaf(q[n], h[n], pb[n] * xv);
  }
  #pragma unroll
  for (int n = 0; n < NE_; ++n) hst[c * NE_ + n] = h[n];
  __syncthreads();

  if (c < NE_) {
    float qq = q[c];
    float q32 = qq * qq; q32 *= q32; q32 *= q32; q32 *= q32; q32 *= q32;  // q^32
    float hi = 0.f;
    for (int cc = 0; cc < 64; ++cc) {
      float cur = hst[cc * NE_ + c];
      hst[cc * NE_ + c] = hi;
      hi = fmaf(q32, hi, cur);
    }
  }
  __syncthreads();

  #pragma unroll
  for (int n = 0; n < NE_; ++n) h[n] = hst[c * NE_ + n];
  const float om = omega[d];
  float* op = mxT + (size_t)bd * L_ + c * 32;
  f32x4 ov;
  #pragma unroll
  for (int k = 0; k < 32; ++k) {
    float xv = bf2f((uint16_t)xin[k >> 3][k & 7]);
    float accv = 0.f;
    #pragma unroll
    for (int n = 0; n < NE_; ++n) {
      h[n] = fmaf(q[n], h[n], pb[n] * xv);
      accv = fmaf(gs[n], h[n], accv);
    }
    ov[k & 3] = accv + om * xv;
    if ((k & 3) == 3) *(f32x4*)(op + (k & ~3)) = ov;
  }
}

// ---------------- RMS norm over D ----------------
__global__ __launch_bounds__(256) void k_rms(const float* __restrict__ mx,
                                             const float* __restrict__ w,
                                             uint16_t* __restrict__ mxn) {
  __shared__ float red[4];
  const size_t row = blockIdx.x;
  const int tid = threadIdx.x;
  float ss = 0.f;
  #pragma unroll
  for (int i = 0; i < 4; ++i) {
    float v = mx[row * D_ + tid + i * 256];
    ss += v * v;
  }
  ss = waveRedSum(ss);
  if ((tid & 63) == 0) red[tid >> 6] = ss;
  __syncthreads();
  ss = red[0] + red[1] + red[2] + red[3];
  const float scale = rsqrtf(ss * (1.f / D_) + EPS_);
  #pragma unroll
  for (int i = 0; i < 4; ++i) {
    int dcol = tid + i * 256;
    mxn[row * D_ + dcol] = f2bf(mx[row * D_ + dcol] * scale * w[dcol]);
  }
}

// ---------------- q/k prep from z ----------------
__global__ __launch_bounds__(256) void k_qkprep(const float* __restrict__ z,
                                                const float* __restrict__ qg,
                                                const float* __restrict__ qb,
                                                uint16_t* __restrict__ q,
                                                uint16_t* __restrict__ k, int n) {
  for (int i = blockIdx.x * 256 + threadIdx.x; i < n; i += gridDim.x * 256) {
    int zc = i & (Z_ - 1);
    float v = z[i];
    q[i] = f2bf((v * qg[zc] + qb[zc]) * 0.08838834764831845f);
    k[i] = f2bf(v * qg[Z_ + zc] + qb[Z_ + zc]);
  }
}

// ==================================================================
// 128x128-tile, BK=32, 4-wave, 2-phase prefetch GEMM, 4 blocks/CU.
//
// Round-6 fix: round-5's launch_bounds(256,5) capped VGPR at ~102 and
// the allocator SPILLED the 64-reg accumulator to scratch (measured:
// VGPR_Count=48, WRITE_SIZE 2.4x, FETCH 1.4x -> dur +28%).  (256,4)
// caps at 128 VGPR (body needs ~90-110, no spill) and still gives
// 4 blocks/CU (LDS 4 x 32 KiB = 128 of 160 KiB).  4 independent
// blocks x ~200 cy/tile issue work covers the ~500 cy residual drain
// (m114 cross-block overlap mechanism).
//
// Swizzle for [128][32] tiles (64 B rows, bank-group = 4*(row&1)+g):
// phys granule = logical ^ ((row>>1)&3) -> 2-way (free).  Staging keeps
// LDS dest linear (gl2lds) and pre-swizzles the GLOBAL source column.
//
// C = A(MxK) @ B(NxK)^T, fused epilogues:
//  MODE 0: V     out = silu(acc + bv[col])               -> bf16 v
//  MODE 1: BASE  acc + bmx[col], split u/z/r/hx (N=4224=33*128)
//  MODE 4: WH    g=silu(acc+hx); out = x + u*(g-x)        -> f32 d_out
// ==================================================================

template <int MODE>
__global__ __launch_bounds__(256, 4) void k_gemm128(
    const uint16_t* __restrict__ A, const uint16_t* __restrict__ Bm,
    int N, int K,
    const float* __restrict__ bias,
    float* __restrict__ outf, uint16_t* __restrict__ outb,
    uint16_t* __restrict__ ubuf, float* __restrict__ zbuf,
    uint16_t* __restrict__ rbuf, float* __restrict__ hxbuf,
    const float* __restrict__ x0) {
  __shared__ uint16_t sm[16384];  // 32 KiB: buf c at c*8192; A +0, B +4096
  const int t = threadIdx.x;
  const int lane = t & 63, wave = t >> 6;
  const int quad = lane >> 4, r16 = lane & 15;
  const int wm = wave >> 1, wn = wave & 1;
  const int bm = blockIdx.x * 128;
  const int bn = blockIdx.y * 128;

  f32x4 acc[4][4];
  const f32x4 zf = {0.f, 0.f, 0.f, 0.f};
  #pragma unroll
  for (int i = 0; i < 4; ++i)
    #pragma unroll
    for (int j = 0; j < 4; ++j) acc[i][j] = zf;

  // staging: thread t -> rows {t>>2, 64+(t>>2)}, phys granule t&3;
  // LDS dest linear; global col pre-swizzled: logical = (t&3)^((t>>3)&3)
  const int sgz = (((t & 3) ^ ((t >> 3) & 3)) << 3);
  const uint16_t* gA = A + (size_t)(bm + (t >> 2)) * K + sgz;
  const uint16_t* gB = Bm + (size_t)(bn + (t >> 2)) * K + sgz;
  const size_t qstep = (size_t)64 * K;
  uint16_t* lA = sm + t * 8;
  uint16_t* lB = sm + 4096 + t * 8;

  // reads: row*32 + ((quad ^ ((row>>1)&3))<<3); row>>1 mod 4 = r16>>1 mod 4
  const int ga = ((quad ^ ((r16 >> 1) & 3)) << 3);
  const int aOff = (wm * 64 + r16) * 32 + ga;
  const int bOff = 4096 + (wn * 64 + r16) * 32 + ga;

#define STAGE(c, kb) do {                                                     \
    gl2lds(gA + (kb), lA + (c) * 8192);                                       \
    gl2lds(gA + qstep + (kb), lA + (c) * 8192 + 2048);                        \
    gl2lds(gB + (kb), lB + (c) * 8192);                                       \
    gl2lds(gB + qstep + (kb), lB + (c) * 8192 + 2048);                        \
  } while (0)

  const int NT = K >> 5;

  STAGE(0, 0);
  __syncthreads();  // vmcnt(0) drain + barrier

  bf16x8 af[4], bfr[4];
  for (int tt = 0; tt < NT; ++tt) {
    const int c = tt & 1;
    const int co = c * 8192;
    if (tt + 1 < NT) STAGE(c ^ 1, (tt + 1) * 32);  // prefetch next tile
    #pragma unroll
    for (int j = 0; j < 4; ++j)
      bfr[j] = *(const bf16x8*)&sm[co + bOff + j * 512];
    #pragma unroll
    for (int i = 0; i < 4; ++i)
      af[i] = *(const bf16x8*)&sm[co + aOff + i * 512];
    #pragma unroll
    for (int i = 0; i < 4; ++i)
      #pragma unroll
      for (int j = 0; j < 4; ++j)
        acc[i][j] = __builtin_amdgcn_mfma_f32_16x16x32_bf16(
            af[i], bfr[j], acc[i][j], 0, 0, 0);
    __syncthreads();  // single vmcnt(0)+barrier per K-tile
  }
#undef STAGE

  // ---- epilogue ----
  #pragma unroll
  for (int i = 0; i < 4; ++i) {
    #pragma unroll
    for (int j = 0; j < 4; ++j) {
      #pragma unroll
      for (int r = 0; r < 4; ++r) {
        const int row = bm + wm * 64 + i * 16 + quad * 4 + r;
        const int col = bn + wn * 64 + j * 16 + r16;
        float val = acc[i][j][r];
        if (MODE == 0) {
          outb[(size_t)row * N + col] = f2bf(siluf_(val + bias[col]));
        } else if (MODE == 1) {
          val += bias[col];
          if (col < D_)                 ubuf[(size_t)row * D_ + col] = f2bf(sigmoidf_(val));
          else if (col < D_ + Z_)       zbuf[(size_t)row * Z_ + (col - D_)] = siluf_(val);
          else if (col < D_ + Z_ + H_)  rbuf[(size_t)row * H_ + (col - D_ - Z_)] = f2bf(siluf_(val));
          else                          hxbuf[(size_t)row * D_ + (col - D_ - Z_ - H_)] = val;
        } else {
          const size_t idx = (size_t)row * N + col;
          float g = siluf_(val + hxbuf[idx]);   // read hx (d_out) ...
          float xv = x0[idx];
          outf[idx] = xv + bf2f(ubuf[idx]) * (g - xv);  // ... then write same addr
        }
      }
    }
  }
}

// ---- fused QK^T + rel_bias + causal softmax -> packed-triangular P (bf16) ----
// Ks rows are 128 elems (256 B): granule XOR-swizzle phys = logical^(row&7);
// staging pre-swizzles the global source column, LDS dest stays linear.
__global__ __launch_bounds__(256) void k_qksm(
    const uint16_t* __restrict__ qg, const uint16_t* __restrict__ kg,
    const float* __restrict__ relb, uint16_t* __restrict__ Pp) {
  __shared__ uint16_t Ks[128 * 128];
  __shared__ float relwin[256];
  const int qt = blockIdx.x;
  const int bl = blockIdx.y;
  const int tid = threadIdx.x;
  const int w = tid >> 6, lane = tid & 63;
  const int quad = lane >> 4, r16 = lane & 15;
  const uint16_t* qb_b = qg + (size_t)bl * L_ * Z_;
  const uint16_t* kb_b = kg + (size_t)bl * L_ * Z_;
  uint16_t* P_b = Pp + (size_t)bl * NPACK_ * TILE_ELEMS_;

  const int ksg = (tid >> 4) * 128 + (((tid & 15) ^ ((tid >> 4) & 7)) << 3);
  const int kg7 = r16 & 7;

  bf16x8 aq[2][4];
  #pragma unroll
  for (int i = 0; i < 2; ++i)
    #pragma unroll
    for (int s = 0; s < 4; ++s)
      aq[i][s] = *(const bf16x8*)&qb_b[(size_t)(qt * 128 + w * 32 + i * 16 + r16) * Z_ +
                                       s * 32 + quad * 8];

  float m8[8], l8[8];
  #pragma unroll
  for (int t = 0; t < 8; ++t) { m8[t] = -3.4e38f; l8[t] = 0.f; }

  const f32x4 zf = {0.f, 0.f, 0.f, 0.f};

  // ---- phase 1: stats ----
  for (int kt = 0; kt <= qt; ++kt) {
    __syncthreads();
    const uint16_t* src = kb_b + (size_t)kt * 128 * Z_;
    #pragma unroll
    for (int s2 = 0; s2 < 8; ++s2)
      gl2lds(src + s2 * 2048 + ksg, Ks + s2 * 2048 + tid * 8);
    if (tid < 255) relwin[tid] = relb[2047 + (kt - qt) * 128 - 127 + tid];
    __syncthreads();
    #pragma unroll
    for (int j = 0; j < 8; ++j) {
      f32x4 a0 = zf, a1 = zf;
      #pragma unroll
      for (int s = 0; s < 4; ++s) {
        bf16x8 bk = *(const bf16x8*)&Ks[(j * 16 + r16) * 128 +
                                        (((s * 4 + quad) ^ kg7) << 3)];
        a0 = __builtin_amdgcn_mfma_f32_16x16x32_bf16(aq[0][s], bk, a0, 0, 0, 0);
        a1 = __builtin_amdgcn_mfma_f32_16x16x32_bf16(aq[1][s], bk, a1, 0, 0, 0);
      }
      #pragma unroll
      for (int i = 0; i < 2; ++i) {
        const f32x4 av = i ? a1 : a0;
        #pragma unroll
        for (int r = 0; r < 4; ++r) {
          const int rloc = w * 32 + i * 16 + quad * 4 + r;
          const int cloc = j * 16 + r16;
          if (kt < qt || cloc <= rloc) {
            const float v = av[r] + relwin[cloc - rloc + 127];
            const int t = i * 4 + r;
            const float mn = fmaxf(m8[t], v);
            l8[t] = l8[t] * __expf(m8[t] - mn) + __expf(v - mn);
            m8[t] = mn;
          }
        }
      }
    }
  }

  #pragma unroll
  for (int t = 0; t < 8; ++t) {
    #pragma unroll
    for (int msk = 1; msk <= 8; msk <<= 1) {
      const float mo = __shfl_xor(m8[t], msk, 64);
      const float lo = __shfl_xor(l8[t], msk, 64);
      const float mn = fmaxf(m8[t], mo);
      l8[t] = l8[t] * __expf(m8[t] - mn) + lo * __expf(mo - mn);
      m8[t] = mn;
    }
    l8[t] = 1.f / l8[t];
  }

  // ---- phase 2: recompute, normalize, write packed P ----
  for (int kt = 0; kt <= qt; ++kt) {
    __syncthreads();
    const uint16_t* src = kb_b + (size_t)kt * 128 * Z_;
    #pragma unroll
    for (int s2 = 0; s2 < 8; ++s2)
      gl2lds(src + s2 * 2048 + ksg, Ks + s2 * 2048 + tid * 8);
    if (tid < 255) relwin[tid] = relb[2047 + (kt - qt) * 128 - 127 + tid];
    __syncthreads();
    uint16_t* Pt = P_b + (size_t)(qt * (qt + 1) / 2 + kt) * TILE_ELEMS_;
    #pragma unroll
    for (int j = 0; j < 8; ++j) {
      f32x4 a0 = zf, a1 = zf;
      #pragma unroll
      for (int s = 0; s < 4; ++s) {
        bf16x8 bk = *(const bf16x8*)&Ks[(j * 16 + r16) * 128 +
                                        (((s * 4 + quad) ^ kg7) << 3)];
        a0 = __builtin_amdgcn_mfma_f32_16x16x32_bf16(aq[0][s], bk, a0, 0, 0, 0);
        a1 = __builtin_amdgcn_mfma_f32_16x16x32_bf16(aq[1][s], bk, a1, 0, 0, 0);
      }
      #pragma unroll
      for (int i = 0; i < 2; ++i) {
        const f32x4 av = i ? a1 : a0;
        #pragma unroll
        for (int r = 0; r < 4; ++r) {
          const int rloc = w * 32 + i * 16 + quad * 4 + r;
          const int cloc = j * 16 + r16;
          const int t = i * 4 + r;
          float p = 0.f;
          if (kt < qt || cloc <= rloc) {
            const float v = av[r] + relwin[cloc - rloc + 127];
            p = __expf(v - m8[t]) * l8[t];
          }
          Pt[rloc * 128 + cloc] = f2bf(p);
        }
      }
    }
  }
}

// ---- PV GEMM: hr = (P @ V) * r, packed-triangular P, in-place over r ----
// BK=32 double-buffered prefetch (1 barrier/step), 32 KiB LDS, 4 blocks/CU
// ((256,4): VGPR cap 128, no accumulator spill).
// Swizzle: phys granule = logical ^ ((row>>1)&3) (2-way free on [*][32]).
// Grid reversed so heavy (large qt) blocks launch first.
__global__ __launch_bounds__(256, 4) void k_pv(
    const uint16_t* __restrict__ Pp, const uint16_t* __restrict__ vT,
    uint16_t* __restrict__ rh) {
  __shared__ uint16_t sm[16384];  // 32 KiB: buf c at c*8192; A +0, B +4096
  const int qt = NTILE_ - 1 - blockIdx.x;   // heavy blocks first
  const int bn = blockIdx.y * 128;
  const int bl = blockIdx.z;
  const uint16_t* Pq = Pp + (size_t)bl * NPACK_ * TILE_ELEMS_ +
                       (size_t)(qt * (qt + 1) / 2) * TILE_ELEMS_;
  const uint16_t* v_b = vT + (size_t)bl * H_ * L_;
  uint16_t* rh_b = rh + (size_t)bl * L_ * H_;

  const int tid = threadIdx.x;
  const int wave = tid >> 6, lane = tid & 63;
  const int quad = lane >> 4, r16 = lane & 15;
  const int wm = wave >> 1, wn = wave & 1;
  const int rowW = wm * 64, colW = wn * 64;

  f32x4 acc[4][4];
  const f32x4 zf = {0.f, 0.f, 0.f, 0.f};
  #pragma unroll
  for (int i = 0; i < 4; ++i)
    #pragma unroll
    for (int j = 0; j < 4; ++j) acc[i][j] = zf;

  const int rA = tid >> 2;
  // staging: phys granule tid&3 -> logical (tid&3)^((rA>>1)&3)
  const int sg = (((tid & 3) ^ ((tid >> 3) & 3)) << 3);
  // reads: phys granule = quad ^ ((row>>1)&3)
  const int gpv = ((quad ^ ((r16 >> 1) & 3)) << 3);

#define PVSTAGE(c, s) do {                                                    \
    const int kt_ = (s) >> 2, ks_ = (s) & 3;                                  \
    const uint16_t* At_ = Pq + (size_t)kt_ * TILE_ELEMS_ + ks_ * 32 + sg;     \
    const uint16_t* Bt_ = v_b + (size_t)(bn + rA) * L_ + kt_ * 128 +          \
                          ks_ * 32 + sg;                                      \
    gl2lds(At_ + rA * 128, sm + (c) * 8192 + tid * 8);                        \
    gl2lds(At_ + (rA + 64) * 128, sm + (c) * 8192 + 2048 + tid * 8);          \
    gl2lds(Bt_, sm + (c) * 8192 + 4096 + tid * 8);                            \
    gl2lds(Bt_ + (size_t)64 * L_, sm + (c) * 8192 + 6144 + tid * 8);          \
  } while (0)

  const int S = 4 * (qt + 1);

  PVSTAGE(0, 0);
  __syncthreads();

  bf16x8 af[4], bfr[4];
  for (int s = 0; s < S; ++s) {
    const int c = s & 1;
    const int co = c * 8192;
    if (s + 1 < S) PVSTAGE(c ^ 1, s + 1);
    #pragma unroll
    for (int j = 0; j < 4; ++j)
      bfr[j] = *(const bf16x8*)&sm[co + 4096 + (colW + j * 16 + r16) * 32 + gpv];
    #pragma unroll
    for (int i = 0; i < 4; ++i)
      af[i] = *(const bf16x8*)&sm[co + (rowW + i * 16 + r16) * 32 + gpv];
    #pragma unroll
    for (int i = 0; i < 4; ++i)
      #pragma unroll
      for (int j = 0; j < 4; ++j)
        acc[i][j] = __builtin_amdgcn_mfma_f32_16x16x32_bf16(af[i], bfr[j], acc[i][j], 0, 0, 0);
    __syncthreads();
  }
#undef PVSTAGE

  #pragma unroll
  for (int i = 0; i < 4; ++i) {
    #pragma unroll
    for (int j = 0; j < 4; ++j) {
      #pragma unroll
      for (int r = 0; r < 4; ++r) {
        const int row = qt * 128 + rowW + i * 16 + quad * 4 + r;
        const int col = bn + colW + j * 16 + r16;
        const size_t idx = (size_t)row * H_ + col;
        const float rv = bf2f(rh_b[idx]);
        rh_b[idx] = f2bf(acc[i][j][r] * rv);
      }
    }
  }
}

extern "C" void kernel_launch(void* const* d_in, const int* in_sizes, int n_in,
                              void* d_out, int out_size, void* d_ws, size_t ws_size,
                              hipStream_t stream) {
  (void)in_sizes; (void)n_in;
  const float* x         = (const float*)d_in[0];
  const float* prior_mean= (const float*)d_in[1];
  const float* prior_logv= (const float*)d_in[2];
  const float* tn_w      = (const float*)d_in[3];
  const float* tn_b      = (const float*)d_in[4];
  const float* delta     = (const float*)d_in[5];
  const float* alpha     = (const float*)d_in[6];
  const float* ema_beta  = (const float*)d_in[7];
  const float* ema_gamma = (const float*)d_in[8];
  const float* omega     = (const float*)d_in[9];
  const float* rms_w     = (const float*)d_in[10];
  const float* Wv        = (const float*)d_in[11];
  const float* bv        = (const float*)d_in[12];
  const float* Wmx       = (const float*)d_in[13];
  const float* bmx       = (const float*)d_in[14];
  const float* Wh        = (const float*)d_in[15];
  const float* qk_gamma  = (const float*)d_in[16];
  const float* qk_beta   = (const float*)d_in[17];
  const float* rel_bias  = (const float*)d_in[18];
  float* out = (float*)d_out;

  const int BL = B_ * L_;
  const size_t MB = 1024 * 1024;
  const size_t REQUIRED = 256 * MB;

  if (ws_size < REQUIRED) {
    k_fallback<<<dim3(4096), dim3(256), 0, stream>>>(out, out_size, (float)(ws_size / MB));
    return;
  }

  char* p = (char*)d_ws;
  // A [0,32): xn (bf16) -> ubuf (bf16)
  uint16_t* xn   = (uint16_t*)(p);
  uint16_t* ubuf = (uint16_t*)(p);
  // B [32,64): s1s2 (4MB, tnorm only) -> xnT -> mxn
  float*    s1g  = (float*)   (p + 32 * MB);
  float*    s2g  = (float*)   (p + 34 * MB);
  uint16_t* xnT  = (uint16_t*)(p + 32 * MB);
  uint16_t* mxn  = (uint16_t*)(p + 32 * MB);
  // C [64,128): vbuf -> mx (f32) -> rbuf/hr (in-place PV)
  uint16_t* vbuf = (uint16_t*)(p + 64 * MB);
  float*    mx   = (float*)   (p + 64 * MB);
  uint16_t* rbuf = (uint16_t*)(p + 64 * MB);
  // D [128,192): wv_b -> vT
  uint16_t* wv_b = (uint16_t*)(p + 128 * MB);
  uint16_t* vT   = (uint16_t*)(p + 128 * MB);
  // E [192,256): wmx_b(8.25) | z(8) | qb(4) | kb(4) | Ppack(35.65)
  uint16_t* wmx_b = (uint16_t*)(p + 192 * MB);
  uint16_t* wh_b  = (uint16_t*)(p + 192 * MB);
  float*    zb    = (float*)   (p + 201 * MB);
  uint16_t* qb    = (uint16_t*)(p + 209 * MB);
  uint16_t* kb2   = (uint16_t*)(p + 213 * MB);
  uint16_t* Ppack = (uint16_t*)(p + 217 * MB);
  // d_out doubles as: mxT f32 (EMA out) -> hx f32 (BASE out) -> out
  float* mxT = out;
  float* hx  = out;

  // 1. weights -> bf16
  k_f2bf<<<dim3(1024), dim3(256), 0, stream>>>(Wv, wv_b, H_ * D_);
  k_f2bf<<<dim3(2048), dim3(256), 0, stream>>>(Wmx, wmx_b, NMX_ * D_);
  // 2. timestep norm (3-phase parallel) -> xn
  k_tnsum<<<dim3(B_ * G_, 16), dim3(256), 0, stream>>>(x, s1g, s2g);
  k_tnscan<<<dim3(B_ * G_), dim3(64), 0, stream>>>(s1g, s2g);
  k_tnnorm<<<dim3(B_ * G_, 16), dim3(256), 0, stream>>>(
      x, s1g, s2g, prior_mean, prior_logv, tn_w, tn_b, xn);
  // 3. xn -> xnT (overwrites dead s1s2)
  k_transpose<uint16_t><<<dim3(D_ / 32, L_ / 32, B_), dim3(256), 0, stream>>>(xn, xnT, L_, D_);
  // 4. v = silu(xn @ Wv^T + bv) -> vbuf
  k_gemm128<0><<<dim3(BL / 128, H_ / 128), dim3(256), 0, stream>>>(
      xn, wv_b, H_, D_, bv, nullptr, vbuf,
      nullptr, nullptr, nullptr, nullptr, nullptr);
  // 5. v -> vT (overwrites dead wv_b)
  k_transpose<uint16_t><<<dim3(H_ / 32, L_ / 32, B_), dim3(256), 0, stream>>>(vbuf, vT, L_, H_);
  // 6. EMA: xnT -> mxT (d_out)
  k_ema<<<dim3(B_ * D_), dim3(64), 0, stream>>>(xnT, delta, alpha, ema_beta, ema_gamma, omega, mxT);
  // 7. mxT -> mx (overwrites dead vbuf)
  k_transpose<float><<<dim3(L_ / 32, D_ / 32, B_), dim3(256), 0, stream>>>(mxT, mx, D_, L_);
  // 8. RMS norm -> mxn (overwrites dead xnT)
  k_rms<<<dim3(BL), dim3(256), 0, stream>>>(mx, rms_w, mxn);
  // 9. BASE GEMM -> u(A), z(E), r(C), hx(d_out)
  k_gemm128<1><<<dim3(BL / 128, NMX_ / 128), dim3(256), 0, stream>>>(
      mxn, wmx_b, NMX_, D_, bmx, nullptr, nullptr,
      ubuf, zb, rbuf, hx, nullptr);
  // 10. q,k from z
  k_qkprep<<<dim3(1024), dim3(256), 0, stream>>>(zb, qk_gamma, qk_beta, qb, kb2, BL * Z_);
  // 11. fused QK+softmax -> packed P (all 8 batches, one dispatch)
  k_qksm<<<dim3(NTILE_, B_), dim3(256), 0, stream>>>(qb, kb2, rel_bias, Ppack);
  // 12. PV GEMM, hr = (P@V)*r in-place over rbuf (one dispatch)
  k_pv<<<dim3(NTILE_, H_ / 128, B_), dim3(256), 0, stream>>>(Ppack, vT, rbuf);
  // 13. Wh -> bf16 (over dead wmx_b)
  k_f2bf<<<dim3(1024), dim3(256), 0, stream>>>(Wh, wh_b, D_ * H_);
  // 14. final: g = silu(hx + hr@Wh^T); out = x + u*(g-x)
  k_gemm128<4><<<dim3(BL / 128, D_ / 128), dim3(256), 0, stream>>>(
      rbuf, wh_b, D_, H_, nullptr, out, nullptr,
      ubuf, nullptr, nullptr, hx, x);
}

// Round 7
// 1157.681 us; speedup vs baseline: 1.2619x; 1.0390x over previous
//
#include <hip/hip_runtime.h>
#include <stdint.h>

#define B_ 8
#define L_ 2048
#define D_ 1024
#define Z_ 128
#define H_ 2048
#define NE_ 16
#define G_ 32
#define MAXPOS_ 2048
#define NMX_ 4224   // D + Z + H + D (u | z | r | hx) = 33 * 128 exactly
#define EPS_ 1e-5f
#define PC_ 2.0f
#define NTILE_ 16            // L/128 q-tiles
#define NPACK_ 136           // 16*17/2 packed causal tiles
#define TILE_ELEMS_ 16384    // 128*128

typedef short bf16x8 __attribute__((ext_vector_type(8)));
typedef float f32x4 __attribute__((ext_vector_type(4)));

__device__ __forceinline__ float bf2f(uint16_t u) {
  union { uint32_t u; float f; } v; v.u = ((uint32_t)u) << 16; return v.f;
}
__device__ __forceinline__ uint16_t f2bf(float f) {
  union { float f; uint32_t u; } v; v.f = f;
  uint32_t r = (v.u + 0x7FFFu + ((v.u >> 16) & 1u)) >> 16;
  return (uint16_t)r;
}
__device__ __forceinline__ float sigmoidf_(float x) { return 1.f / (1.f + __expf(-x)); }
__device__ __forceinline__ float siluf_(float x) { return x / (1.f + __expf(-x)); }

__device__ __forceinline__ float waveRedSum(float v) {
  #pragma unroll
  for (int m = 32; m; m >>= 1) v += __shfl_xor(v, m, 64);
  return v;
}

// async global->LDS, 16 bytes per lane; lds dst must be waveBase + lane*16
__device__ __forceinline__ void gl2lds(const uint16_t* g, uint16_t* l) {
  __builtin_amdgcn_global_load_lds(
      (const __attribute__((address_space(1))) void*)g,
      (__attribute__((address_space(3))) void*)l, 16, 0, 0);
}

// ---------------- fallback when workspace too small ----------------
__global__ __launch_bounds__(256) void k_fallback(float* __restrict__ out, int n, float wsmb) {
  for (int i = blockIdx.x * 256 + threadIdx.x; i < n; i += gridDim.x * 256)
    out[i] = (i == 0) ? wsmb : 0.f;
}

// ---------------- fp32 -> bf16 conversion (weights) ----------------
__global__ __launch_bounds__(256) void k_f2bf(const float* __restrict__ src,
                                              uint16_t* __restrict__ dst, int n) {
  for (int i = blockIdx.x * 256 + threadIdx.x; i < n; i += gridDim.x * 256)
    dst[i] = f2bf(src[i]);
}

// ---------------- TimestepNorm, parallel 3-phase ----------------
__global__ __launch_bounds__(256) void k_tnsum(const float* __restrict__ x,
                                               float* __restrict__ s1g,
                                               float* __restrict__ s2g) {
  const int bg = blockIdx.x;
  const int b = bg / G_, g = bg % G_;
  const int tid = threadIdx.x;
  const int j = tid & 31;
  const int lsub = tid >> 5;
  #pragma unroll
  for (int i = 0; i < 16; ++i) {
    const int l = blockIdx.y * 128 + i * 8 + lsub;
    float v = x[((size_t)(b * L_ + l)) * D_ + g * 32 + j];
    float a = v, sq = v * v;
    #pragma unroll
    for (int m = 1; m <= 16; m <<= 1) { a += __shfl_xor(a, m, 64); sq += __shfl_xor(sq, m, 64); }
    if (j == 0) { s1g[(size_t)bg * L_ + l] = a; s2g[(size_t)bg * L_ + l] = sq; }
  }
}

__global__ __launch_bounds__(64) void k_tnscan(float* __restrict__ s1g,
                                               float* __restrict__ s2g) {
  const int bg = blockIdx.x;
  const int lane = threadIdx.x;
  #pragma unroll
  for (int pass = 0; pass < 2; ++pass) {
    float* gp = (pass ? s2g : s1g) + (size_t)bg * L_;
    float loc[32];
    const int b0 = lane * 32;
    float tot = 0.f;
    #pragma unroll
    for (int t = 0; t < 32; ++t) { loc[t] = gp[b0 + t]; tot += loc[t]; }
    float incl = tot;
    #pragma unroll
    for (int off = 1; off < 64; off <<= 1) {
      float nv = __shfl_up(incl, off, 64);
      if (lane >= off) incl += nv;
    }
    float run = incl - tot;
    #pragma unroll
    for (int t = 0; t < 32; ++t) { run += loc[t]; gp[b0 + t] = run; }
  }
}

__global__ __launch_bounds__(256) void k_tnnorm(const float* __restrict__ x,
                                                const float* __restrict__ s1g,
                                                const float* __restrict__ s2g,
                                                const float* __restrict__ pm,
                                                const float* __restrict__ plv,
                                                const float* __restrict__ w,
                                                const float* __restrict__ bias,
                                                uint16_t* __restrict__ xn) {
  const int bg = blockIdx.x;
  const int b = bg / G_, g = bg % G_;
  const int tid = threadIdx.x;
  const int j = tid & 31;
  const int lsub = tid >> 5;
  const float pmv = pm[g];
  const float pvv = __expf(plv[g]);
  const float wj = w[g * 32 + j];
  const float bj = bias[g * 32 + j];
  const float pterm = PC_ * (pvv + pmv * pmv);
  #pragma unroll
  for (int i = 0; i < 16; ++i) {
    const int l = blockIdx.y * 128 + i * 8 + lsub;
    const size_t idx = ((size_t)(b * L_ + l)) * D_ + g * 32 + j;
    const float v = x[idx];
    const float cnt = PC_ + 32.f * (float)(l + 1);
    const float mean = (PC_ * pmv + s1g[(size_t)bg * L_ + l]) / cnt;
    const float var = (pterm + s2g[(size_t)bg * L_ + l]) / cnt - mean * mean;
    xn[idx] = f2bf((v - mean) * rsqrtf(var + EPS_) * wj + bj);
  }
}

// ---------------- vectorized 64x64-tile transposes ----------------
// bf16: 16B/lane global loads+stores, scalar LDS w/ +1 padding (~2-way).
__global__ __launch_bounds__(256) void k_tp16(const uint16_t* __restrict__ src,
                                              uint16_t* __restrict__ dst, int R, int C) {
  __shared__ uint16_t tile[64 * 65];
  const size_t batch = (size_t)R * C * blockIdx.z;
  const int c0 = blockIdx.x * 64, r0 = blockIdx.y * 64;
  const int t = threadIdx.x;
  const int rr = t >> 3;          // 0..31
  const int cc = (t & 7) * 8;     // 0,8,..,56
  #pragma unroll
  for (int p = 0; p < 2; ++p) {
    const int row = p * 32 + rr;
    bf16x8 v = *(const bf16x8*)&src[batch + (size_t)(r0 + row) * C + c0 + cc];
    #pragma unroll
    for (int i = 0; i < 8; ++i) tile[(cc + i) * 65 + row] = (uint16_t)v[i];
  }
  __syncthreads();
  #pragma unroll
  for (int p = 0; p < 2; ++p) {
    const int crow = p * 32 + rr;
    bf16x8 o;
    #pragma unroll
    for (int i = 0; i < 8; ++i) o[i] = (short)tile[crow * 65 + cc + i];
    *(bf16x8*)&dst[batch + (size_t)(c0 + crow) * R + r0 + cc] = o;
  }
}

// f32: float4 global loads+stores.
__global__ __launch_bounds__(256) void k_tpf32(const float* __restrict__ src,
                                               float* __restrict__ dst, int R, int C) {
  __shared__ float tile[64 * 65];
  const size_t batch = (size_t)R * C * blockIdx.z;
  const int c0 = blockIdx.x * 64, r0 = blockIdx.y * 64;
  const int t = threadIdx.x;
  const int rr = t >> 4;          // 0..15
  const int cc = (t & 15) * 4;    // 0..60
  #pragma unroll
  for (int p = 0; p < 4; ++p) {
    const int row = p * 16 + rr;
    f32x4 v = *(const f32x4*)&src[batch + (size_t)(r0 + row) * C + c0 + cc];
    #pragma unroll
    for (int i = 0; i < 4; ++i) tile[(cc + i) * 65 + row] = v[i];
  }
  __syncthreads();
  #pragma unroll
  for (int p = 0; p < 4; ++p) {
    const int crow = p * 16 + rr;
    f32x4 o;
    #pragma unroll
    for (int i = 0; i < 4; ++i) o[i] = tile[crow * 65 + cc + i];
    *(f32x4*)&dst[batch + (size_t)(c0 + crow) * R + r0 + cc] = o;
  }
}

// ---------------- MultiHeadEMA via chunked linear recurrence ----------------
__global__ __launch_bounds__(64) void k_ema(const uint16_t* __restrict__ xnT,
                                            const float* __restrict__ delta,
                                            const float* __restrict__ alpha,
                                            const float* __restrict__ beta,
                                            const float* __restrict__ gamma,
                                            const float* __restrict__ omega,
                                            float* __restrict__ mxT) {
  __shared__ float hst[64 * NE_];
  const int bd = blockIdx.x;
  const int d = bd & (D_ - 1);
  const int c = threadIdx.x;

  float q[NE_], pb[NE_], gs[NE_];
  #pragma unroll
  for (int n = 0; n < NE_; ++n) {
    float p = sigmoidf_(delta[d * NE_ + n]);
    float a = sigmoidf_(alpha[d * NE_ + n]);
    q[n] = 1.f - p * a;
    pb[n] = p * beta[d * NE_ + n];
    gs[n] = gamma[d * NE_ + n] * 0.25f;
  }

  const uint16_t* xp = xnT + (size_t)bd * L_ + c * 32;
  bf16x8 xin[4];
  #pragma unroll
  for (int s = 0; s < 4; ++s) xin[s] = *(const bf16x8*)(xp + s * 8);

  float h[NE_];
  #pragma unroll
  for (int n = 0; n < NE_; ++n) h[n] = 0.f;

  #pragma unroll
  for (int k = 0; k < 32; ++k) {
    float xv = bf2f((uint16_t)xin[k >> 3][k & 7]);
    #pragma unroll
    for (int n = 0; n < NE_; ++n) h[n] = fmaf(q[n], h[n], pb[n] * xv);
  }
  #pragma unroll
  for (int n = 0; n < NE_; ++n) hst[c * NE_ + n] = h[n];
  __syncthreads();

  if (c < NE_) {
    float qq = q[c];
    float q32 = qq * qq; q32 *= q32; q32 *= q32; q32 *= q32; q32 *= q32;  // q^32
    float hi = 0.f;
    for (int cc = 0; cc < 64; ++cc) {
      float cur = hst[cc * NE_ + c];
      hst[cc * NE_ + c] = hi;
      hi = fmaf(q32, hi, cur);
    }
  }
  __syncthreads();

  #pragma unroll
  for (int n = 0; n < NE_; ++n) h[n] = hst[c * NE_ + n];
  const float om = omega[d];
  float* op = mxT + (size_t)bd * L_ + c * 32;
  f32x4 ov;
  #pragma unroll
  for (int k = 0; k < 32; ++k) {
    float xv = bf2f((uint16_t)xin[k >> 3][k & 7]);
    float accv = 0.f;
    #pragma unroll
    for (int n = 0; n < NE_; ++n) {
      h[n] = fmaf(q[n], h[n], pb[n] * xv);
      accv = fmaf(gs[n], h[n], accv);
    }
    ov[k & 3] = accv + om * xv;
    if ((k & 3) == 3) *(f32x4*)(op + (k & ~3)) = ov;
  }
}

// ---------------- RMS norm over D ----------------
__global__ __launch_bounds__(256) void k_rms(const float* __restrict__ mx,
                                             const float* __restrict__ w,
                                             uint16_t* __restrict__ mxn) {
  __shared__ float red[4];
  const size_t row = blockIdx.x;
  const int tid = threadIdx.x;
  float ss = 0.f;
  #pragma unroll
  for (int i = 0; i < 4; ++i) {
    float v = mx[row * D_ + tid + i * 256];
    ss += v * v;
  }
  ss = waveRedSum(ss);
  if ((tid & 63) == 0) red[tid >> 6] = ss;
  __syncthreads();
  ss = red[0] + red[1] + red[2] + red[3];
  const float scale = rsqrtf(ss * (1.f / D_) + EPS_);
  #pragma unroll
  for (int i = 0; i < 4; ++i) {
    int dcol = tid + i * 256;
    mxn[row * D_ + dcol] = f2bf(mx[row * D_ + dcol] * scale * w[dcol]);
  }
}

// ---------------- q/k prep from z ----------------
__global__ __launch_bounds__(256) void k_qkprep(const float* __restrict__ z,
                                                const float* __restrict__ qg,
                                                const float* __restrict__ qb,
                                                uint16_t* __restrict__ q,
                                                uint16_t* __restrict__ k, int n) {
  for (int i = blockIdx.x * 256 + threadIdx.x; i < n; i += gridDim.x * 256) {
    int zc = i & (Z_ - 1);
    float v = z[i];
    q[i] = f2bf((v * qg[zc] + qb[zc]) * 0.08838834764831845f);
    k[i] = f2bf(v * qg[Z_ + zc] + qb[Z_ + zc]);
  }
}

// ==================================================================
// 128x128-tile, BK=32, 4-wave, 2-phase prefetch GEMM, 4 blocks/CU.
// (round-6 structure, unchanged main loop: ~606 TF on BASE)
//
// Round-7: MODE 0 (V) writes its output TRANSPOSED directly (vT[h][l])
// via an LDS round-trip in the epilogue — eliminates the separate
// v->vT transpose kernel (~134 MB round trip).  sm grown to 17408
// elems (34.8 KB) for the 128x[136-stride] transpose tile; still
// 4 blocks/CU (139 KB of 160).
//
// C = A(MxK) @ B(NxK)^T, fused epilogues:
//  MODE 0: V     vT[b][h][l] = silu(acc + bv[h])         (transposed)
//  MODE 1: BASE  acc + bmx[col], split u/z/r/hx (N=4224=33*128)
//  MODE 4: WH    g=silu(acc+hx); out = x + u*(g-x)        -> f32 d_out
// ==================================================================

template <int MODE>
__global__ __launch_bounds__(256, 4) void k_gemm128(
    const uint16_t* __restrict__ A, const uint16_t* __restrict__ Bm,
    int N, int K,
    const float* __restrict__ bias,
    float* __restrict__ outf, uint16_t* __restrict__ outb,
    uint16_t* __restrict__ ubuf, float* __restrict__ zbuf,
    uint16_t* __restrict__ rbuf, float* __restrict__ hxbuf,
    const float* __restrict__ x0) {
  __shared__ uint16_t sm[17408];  // 34.8 KiB: dbuf at 0/8192; MODE0 epi reuses all
  const int t = threadIdx.x;
  const int lane = t & 63, wave = t >> 6;
  const int quad = lane >> 4, r16 = lane & 15;
  const int wm = wave >> 1, wn = wave & 1;
  const int bm = blockIdx.x * 128;
  const int bn = blockIdx.y * 128;

  f32x4 acc[4][4];
  const f32x4 zf = {0.f, 0.f, 0.f, 0.f};
  #pragma unroll
  for (int i = 0; i < 4; ++i)
    #pragma unroll
    for (int j = 0; j < 4; ++j) acc[i][j] = zf;

  // staging: thread t -> rows {t>>2, 64+(t>>2)}, phys granule t&3;
  // LDS dest linear; global col pre-swizzled: logical = (t&3)^((t>>3)&3)
  const int sgz = (((t & 3) ^ ((t >> 3) & 3)) << 3);
  const uint16_t* gA = A + (size_t)(bm + (t >> 2)) * K + sgz;
  const uint16_t* gB = Bm + (size_t)(bn + (t >> 2)) * K + sgz;
  const size_t qstep = (size_t)64 * K;
  uint16_t* lA = sm + t * 8;
  uint16_t* lB = sm + 4096 + t * 8;

  // reads: row*32 + ((quad ^ ((row>>1)&3))<<3); row>>1 mod 4 = r16>>1 mod 4
  const int ga = ((quad ^ ((r16 >> 1) & 3)) << 3);
  const int aOff = (wm * 64 + r16) * 32 + ga;
  const int bOff = 4096 + (wn * 64 + r16) * 32 + ga;

#define STAGE(c, kb) do {                                                     \
    gl2lds(gA + (kb), lA + (c) * 8192);                                       \
    gl2lds(gA + qstep + (kb), lA + (c) * 8192 + 2048);                        \
    gl2lds(gB + (kb), lB + (c) * 8192);                                       \
    gl2lds(gB + qstep + (kb), lB + (c) * 8192 + 2048);                        \
  } while (0)

  const int NT = K >> 5;

  STAGE(0, 0);
  __syncthreads();  // vmcnt(0) drain + barrier

  bf16x8 af[4], bfr[4];
  for (int tt = 0; tt < NT; ++tt) {
    const int c = tt & 1;
    const int co = c * 8192;
    if (tt + 1 < NT) STAGE(c ^ 1, (tt + 1) * 32);  // prefetch next tile
    #pragma unroll
    for (int j = 0; j < 4; ++j)
      bfr[j] = *(const bf16x8*)&sm[co + bOff + j * 512];
    #pragma unroll
    for (int i = 0; i < 4; ++i)
      af[i] = *(const bf16x8*)&sm[co + aOff + i * 512];
    #pragma unroll
    for (int i = 0; i < 4; ++i)
      #pragma unroll
      for (int j = 0; j < 4; ++j)
        acc[i][j] = __builtin_amdgcn_mfma_f32_16x16x32_bf16(
            af[i], bfr[j], acc[i][j], 0, 0, 0);
    __syncthreads();  // single vmcnt(0)+barrier per K-tile
  }
#undef STAGE

  // ---- epilogue ----
  if (MODE == 0) {
    // silu+bias, store transposed into sm[h][l] (row stride 136 elems;
    // 16B-aligned rows for vector readback), then coalesced 16B writes
    // to vT[b][h][l].
    #pragma unroll
    for (int i = 0; i < 4; ++i)
      #pragma unroll
      for (int j = 0; j < 4; ++j)
        #pragma unroll
        for (int r = 0; r < 4; ++r) {
          const int hloc = wn * 64 + j * 16 + r16;
          const int lloc = wm * 64 + i * 16 + quad * 4 + r;
          sm[hloc * 136 + lloc] = f2bf(siluf_(acc[i][j][r] + bias[bn + hloc]));
        }
    __syncthreads();
    const int bb = bm >> 11;            // batch index (tile never crosses)
    const int lb = bm & 2047;           // l offset within batch
    uint16_t* vTb = outb + (size_t)bb * H_ * L_;
    #pragma unroll
    for (int p = 0; p < 8; ++p) {
      const int hloc = p * 16 + (t >> 4);
      const int l0 = (t & 15) * 8;
      bf16x8 v = *(const bf16x8*)&sm[hloc * 136 + l0];
      *(bf16x8*)&vTb[(size_t)(bn + hloc) * L_ + lb + l0] = v;
    }
  } else {
    #pragma unroll
    for (int i = 0; i < 4; ++i) {
      #pragma unroll
      for (int j = 0; j < 4; ++j) {
        #pragma unroll
        for (int r = 0; r < 4; ++r) {
          const int row = bm + wm * 64 + i * 16 + quad * 4 + r;
          const int col = bn + wn * 64 + j * 16 + r16;
          float val = acc[i][j][r];
          if (MODE == 1) {
            val += bias[col];
            if (col < D_)                 ubuf[(size_t)row * D_ + col] = f2bf(sigmoidf_(val));
            else if (col < D_ + Z_)       zbuf[(size_t)row * Z_ + (col - D_)] = siluf_(val);
            else if (col < D_ + Z_ + H_)  rbuf[(size_t)row * H_ + (col - D_ - Z_)] = f2bf(siluf_(val));
            else                          hxbuf[(size_t)row * D_ + (col - D_ - Z_ - H_)] = val;
          } else {
            const size_t idx = (size_t)row * N + col;
            float g = siluf_(val + hxbuf[idx]);   // read hx (d_out) ...
            float xv = x0[idx];
            outf[idx] = xv + bf2f(ubuf[idx]) * (g - xv);  // ... then write same addr
          }
        }
      }
    }
  }
}

// ---- fused QK^T + rel_bias + causal softmax -> packed-triangular P (bf16) ----
// Ks rows are 128 elems (256 B): granule XOR-swizzle phys = logical^(row&7);
// staging pre-swizzles the global source column, LDS dest stays linear.
__global__ __launch_bounds__(256) void k_qksm(
    const uint16_t* __restrict__ qg, const uint16_t* __restrict__ kg,
    const float* __restrict__ relb, uint16_t* __restrict__ Pp) {
  __shared__ uint16_t Ks[128 * 128];
  __shared__ float relwin[256];
  const int qt = blockIdx.x;
  const int bl = blockIdx.y;
  const int tid = threadIdx.x;
  const int w = tid >> 6, lane = tid & 63;
  const int quad = lane >> 4, r16 = lane & 15;
  const uint16_t* qb_b = qg + (size_t)bl * L_ * Z_;
  const uint16_t* kb_b = kg + (size_t)bl * L_ * Z_;
  uint16_t* P_b = Pp + (size_t)bl * NPACK_ * TILE_ELEMS_;

  const int ksg = (tid >> 4) * 128 + (((tid & 15) ^ ((tid >> 4) & 7)) << 3);
  const int kg7 = r16 & 7;

  bf16x8 aq[2][4];
  #pragma unroll
  for (int i = 0; i < 2; ++i)
    #pragma unroll
    for (int s = 0; s < 4; ++s)
      aq[i][s] = *(const bf16x8*)&qb_b[(size_t)(qt * 128 + w * 32 + i * 16 + r16) * Z_ +
                                       s * 32 + quad * 8];

  float m8[8], l8[8];
  #pragma unroll
  for (int t = 0; t < 8; ++t) { m8[t] = -3.4e38f; l8[t] = 0.f; }

  const f32x4 zf = {0.f, 0.f, 0.f, 0.f};

  // ---- phase 1: stats ----
  for (int kt = 0; kt <= qt; ++kt) {
    __syncthreads();
    const uint16_t* src = kb_b + (size_t)kt * 128 * Z_;
    #pragma unroll
    for (int s2 = 0; s2 < 8; ++s2)
      gl2lds(src + s2 * 2048 + ksg, Ks + s2 * 2048 + tid * 8);
    if (tid < 255) relwin[tid] = relb[2047 + (kt - qt) * 128 - 127 + tid];
    __syncthreads();
    #pragma unroll
    for (int j = 0; j < 8; ++j) {
      f32x4 a0 = zf, a1 = zf;
      #pragma unroll
      for (int s = 0; s < 4; ++s) {
        bf16x8 bk = *(const bf16x8*)&Ks[(j * 16 + r16) * 128 +
                                        (((s * 4 + quad) ^ kg7) << 3)];
        a0 = __builtin_amdgcn_mfma_f32_16x16x32_bf16(aq[0][s], bk, a0, 0, 0, 0);
        a1 = __builtin_amdgcn_mfma_f32_16x16x32_bf16(aq[1][s], bk, a1, 0, 0, 0);
      }
      #pragma unroll
      for (int i = 0; i < 2; ++i) {
        const f32x4 av = i ? a1 : a0;
        #pragma unroll
        for (int r = 0; r < 4; ++r) {
          const int rloc = w * 32 + i * 16 + quad * 4 + r;
          const int cloc = j * 16 + r16;
          if (kt < qt || cloc <= rloc) {
            const float v = av[r] + relwin[cloc - rloc + 127];
            const int t = i * 4 + r;
            const float mn = fmaxf(m8[t], v);
            l8[t] = l8[t] * __expf(m8[t] - mn) + __expf(v - mn);
            m8[t] = mn;
          }
        }
      }
    }
  }

  #pragma unroll
  for (int t = 0; t < 8; ++t) {
    #pragma unroll
    for (int msk = 1; msk <= 8; msk <<= 1) {
      const float mo = __shfl_xor(m8[t], msk, 64);
      const float lo = __shfl_xor(l8[t], msk, 64);
      const float mn = fmaxf(m8[t], mo);
      l8[t] = l8[t] * __expf(m8[t] - mn) + lo * __expf(mo - mn);
      m8[t] = mn;
    }
    l8[t] = 1.f / l8[t];
  }

  // ---- phase 2: recompute, normalize, write packed P ----
  for (int kt = 0; kt <= qt; ++kt) {
    __syncthreads();
    const uint16_t* src = kb_b + (size_t)kt * 128 * Z_;
    #pragma unroll
    for (int s2 = 0; s2 < 8; ++s2)
      gl2lds(src + s2 * 2048 + ksg, Ks + s2 * 2048 + tid * 8);
    if (tid < 255) relwin[tid] = relb[2047 + (kt - qt) * 128 - 127 + tid];
    __syncthreads();
    uint16_t* Pt = P_b + (size_t)(qt * (qt + 1) / 2 + kt) * TILE_ELEMS_;
    #pragma unroll
    for (int j = 0; j < 8; ++j) {
      f32x4 a0 = zf, a1 = zf;
      #pragma unroll
      for (int s = 0; s < 4; ++s) {
        bf16x8 bk = *(const bf16x8*)&Ks[(j * 16 + r16) * 128 +
                                        (((s * 4 + quad) ^ kg7) << 3)];
        a0 = __builtin_amdgcn_mfma_f32_16x16x32_bf16(aq[0][s], bk, a0, 0, 0, 0);
        a1 = __builtin_amdgcn_mfma_f32_16x16x32_bf16(aq[1][s], bk, a1, 0, 0, 0);
      }
      #pragma unroll
      for (int i = 0; i < 2; ++i) {
        const f32x4 av = i ? a1 : a0;
        #pragma unroll
        for (int r = 0; r < 4; ++r) {
          const int rloc = w * 32 + i * 16 + quad * 4 + r;
          const int cloc = j * 16 + r16;
          const int t = i * 4 + r;
          float p = 0.f;
          if (kt < qt || cloc <= rloc) {
            const float v = av[r] + relwin[cloc - rloc + 127];
            p = __expf(v - m8[t]) * l8[t];
          }
          Pt[rloc * 128 + cloc] = f2bf(p);
        }
      }
    }
  }
}

// ---- PV GEMM: hr = (P @ V) * r, packed-triangular P, in-place over r ----
// BK=32 double-buffered prefetch (1 barrier/step), 32 KiB LDS, 4 blocks/CU.
// Swizzle: phys granule = logical ^ ((row>>1)&3) (2-way free on [*][32]).
// Grid reversed so heavy (large qt) blocks launch first.
__global__ __launch_bounds__(256, 4) void k_pv(
    const uint16_t* __restrict__ Pp, const uint16_t* __restrict__ vT,
    uint16_t* __restrict__ rh) {
  __shared__ uint16_t sm[16384];  // 32 KiB: buf c at c*8192; A +0, B +4096
  const int qt = NTILE_ - 1 - blockIdx.x;   // heavy blocks first
  const int bn = blockIdx.y * 128;
  const int bl = blockIdx.z;
  const uint16_t* Pq = Pp + (size_t)bl * NPACK_ * TILE_ELEMS_ +
                       (size_t)(qt * (qt + 1) / 2) * TILE_ELEMS_;
  const uint16_t* v_b = vT + (size_t)bl * H_ * L_;
  uint16_t* rh_b = rh + (size_t)bl * L_ * H_;

  const int tid = threadIdx.x;
  const int wave = tid >> 6, lane = tid & 63;
  const int quad = lane >> 4, r16 = lane & 15;
  const int wm = wave >> 1, wn = wave & 1;
  const int rowW = wm * 64, colW = wn * 64;

  f32x4 acc[4][4];
  const f32x4 zf = {0.f, 0.f, 0.f, 0.f};
  #pragma unroll
  for (int i = 0; i < 4; ++i)
    #pragma unroll
    for (int j = 0; j < 4; ++j) acc[i][j] = zf;

  const int rA = tid >> 2;
  // staging: phys granule tid&3 -> logical (tid&3)^((rA>>1)&3)
  const int sg = (((tid & 3) ^ ((tid >> 3) & 3)) << 3);
  // reads: phys granule = quad ^ ((row>>1)&3)
  const int gpv = ((quad ^ ((r16 >> 1) & 3)) << 3);

#define PVSTAGE(c, s) do {                                                    \
    const int kt_ = (s) >> 2, ks_ = (s) & 3;                                  \
    const uint16_t* At_ = Pq + (size_t)kt_ * TILE_ELEMS_ + ks_ * 32 + sg;     \
    const uint16_t* Bt_ = v_b + (size_t)(bn + rA) * L_ + kt_ * 128 +          \
                          ks_ * 32 + sg;                                      \
    gl2lds(At_ + rA * 128, sm + (c) * 8192 + tid * 8);                        \
    gl2lds(At_ + (rA + 64) * 128, sm + (c) * 8192 + 2048 + tid * 8);          \
    gl2lds(Bt_, sm + (c) * 8192 + 4096 + tid * 8);                            \
    gl2lds(Bt_ + (size_t)64 * L_, sm + (c) * 8192 + 6144 + tid * 8);          \
  } while (0)

  const int S = 4 * (qt + 1);

  PVSTAGE(0, 0);
  __syncthreads();

  bf16x8 af[4], bfr[4];
  for (int s = 0; s < S; ++s) {
    const int c = s & 1;
    const int co = c * 8192;
    if (s + 1 < S) PVSTAGE(c ^ 1, s + 1);
    #pragma unroll
    for (int j = 0; j < 4; ++j)
      bfr[j] = *(const bf16x8*)&sm[co + 4096 + (colW + j * 16 + r16) * 32 + gpv];
    #pragma unroll
    for (int i = 0; i < 4; ++i)
      af[i] = *(const bf16x8*)&sm[co + (rowW + i * 16 + r16) * 32 + gpv];
    #pragma unroll
    for (int i = 0; i < 4; ++i)
      #pragma unroll
      for (int j = 0; j < 4; ++j)
        acc[i][j] = __builtin_amdgcn_mfma_f32_16x16x32_bf16(af[i], bfr[j], acc[i][j], 0, 0, 0);
    __syncthreads();
  }
#undef PVSTAGE

  #pragma unroll
  for (int i = 0; i < 4; ++i) {
    #pragma unroll
    for (int j = 0; j < 4; ++j) {
      #pragma unroll
      for (int r = 0; r < 4; ++r) {
        const int row = qt * 128 + rowW + i * 16 + quad * 4 + r;
        const int col = bn + colW + j * 16 + r16;
        const size_t idx = (size_t)row * H_ + col;
        const float rv = bf2f(rh_b[idx]);
        rh_b[idx] = f2bf(acc[i][j][r] * rv);
      }
    }
  }
}

extern "C" void kernel_launch(void* const* d_in, const int* in_sizes, int n_in,
                              void* d_out, int out_size, void* d_ws, size_t ws_size,
                              hipStream_t stream) {
  (void)in_sizes; (void)n_in;
  const float* x         = (const float*)d_in[0];
  const float* prior_mean= (const float*)d_in[1];
  const float* prior_logv= (const float*)d_in[2];
  const float* tn_w      = (const float*)d_in[3];
  const float* tn_b      = (const float*)d_in[4];
  const float* delta     = (const float*)d_in[5];
  const float* alpha     = (const float*)d_in[6];
  const float* ema_beta  = (const float*)d_in[7];
  const float* ema_gamma = (const float*)d_in[8];
  const float* omega     = (const float*)d_in[9];
  const float* rms_w     = (const float*)d_in[10];
  const float* Wv        = (const float*)d_in[11];
  const float* bv        = (const float*)d_in[12];
  const float* Wmx       = (const float*)d_in[13];
  const float* bmx       = (const float*)d_in[14];
  const float* Wh        = (const float*)d_in[15];
  const float* qk_gamma  = (const float*)d_in[16];
  const float* qk_beta   = (const float*)d_in[17];
  const float* rel_bias  = (const float*)d_in[18];
  float* out = (float*)d_out;

  const int BL = B_ * L_;
  const size_t MB = 1024 * 1024;
  const size_t REQUIRED = 256 * MB;

  if (ws_size < REQUIRED) {
    k_fallback<<<dim3(4096), dim3(256), 0, stream>>>(out, out_size, (float)(ws_size / MB));
    return;
  }

  char* p = (char*)d_ws;
  // A [0,32): xn (bf16) -> ubuf (bf16)
  uint16_t* xn   = (uint16_t*)(p);
  uint16_t* ubuf = (uint16_t*)(p);
  // B [32,64): s1s2 (4MB, tnorm only) -> xnT -> mxn
  float*    s1g  = (float*)   (p + 32 * MB);
  float*    s2g  = (float*)   (p + 34 * MB);
  uint16_t* xnT  = (uint16_t*)(p + 32 * MB);
  uint16_t* mxn  = (uint16_t*)(p + 32 * MB);
  // C [64,128): vT (64 MiB exactly; written by V GEMM, read by k_pv)
  uint16_t* vT   = (uint16_t*)(p + 64 * MB);
  // D [128,192): wv_b (steps 1-4) -> mx f32 (7-8) -> rbuf/hr (9-14)
  uint16_t* wv_b = (uint16_t*)(p + 128 * MB);
  float*    mx   = (float*)   (p + 128 * MB);
  uint16_t* rbuf = (uint16_t*)(p + 128 * MB);
  // E [192,256): wmx_b(8.25) | z(8) | qb(4) | kb(4) | Ppack(35.65)
  uint16_t* wmx_b = (uint16_t*)(p + 192 * MB);
  uint16_t* wh_b  = (uint16_t*)(p + 192 * MB);
  float*    zb    = (float*)   (p + 201 * MB);
  uint16_t* qb    = (uint16_t*)(p + 209 * MB);
  uint16_t* kb2   = (uint16_t*)(p + 213 * MB);
  uint16_t* Ppack = (uint16_t*)(p + 217 * MB);
  // d_out doubles as: mxT f32 (EMA out) -> hx f32 (BASE out) -> out
  float* mxT = out;
  float* hx  = out;

  // 1. weights -> bf16
  k_f2bf<<<dim3(1024), dim3(256), 0, stream>>>(Wv, wv_b, H_ * D_);
  k_f2bf<<<dim3(2048), dim3(256), 0, stream>>>(Wmx, wmx_b, NMX_ * D_);
  // 2. timestep norm (3-phase parallel) -> xn
  k_tnsum<<<dim3(B_ * G_, 16), dim3(256), 0, stream>>>(x, s1g, s2g);
  k_tnscan<<<dim3(B_ * G_), dim3(64), 0, stream>>>(s1g, s2g);
  k_tnnorm<<<dim3(B_ * G_, 16), dim3(256), 0, stream>>>(
      x, s1g, s2g, prior_mean, prior_logv, tn_w, tn_b, xn);
  // 3. xn -> xnT (vectorized 64x64 transpose; overwrites dead s1s2)
  k_tp16<<<dim3(D_ / 64, L_ / 64, B_), dim3(256), 0, stream>>>(xn, xnT, L_, D_);
  // 4. v = silu(xn @ Wv^T + bv), written TRANSPOSED -> vT (C)
  k_gemm128<0><<<dim3(BL / 128, H_ / 128), dim3(256), 0, stream>>>(
      xn, wv_b, H_, D_, bv, nullptr, vT,
      nullptr, nullptr, nullptr, nullptr, nullptr);
  // 5. EMA: xnT -> mxT (d_out)
  k_ema<<<dim3(B_ * D_), dim3(64), 0, stream>>>(xnT, delta, alpha, ema_beta, ema_gamma, omega, mxT);
  // 6. mxT -> mx (vectorized f32 transpose; overwrites dead wv_b)
  k_tpf32<<<dim3(L_ / 64, D_ / 64, B_), dim3(256), 0, stream>>>(mxT, mx, D_, L_);
  // 7. RMS norm -> mxn (overwrites dead xnT)
  k_rms<<<dim3(BL), dim3(256), 0, stream>>>(mx, rms_w, mxn);
  // 8. BASE GEMM -> u(A), z(E), r(D), hx(d_out)
  k_gemm128<1><<<dim3(BL / 128, NMX_ / 128), dim3(256), 0, stream>>>(
      mxn, wmx_b, NMX_, D_, bmx, nullptr, nullptr,
      ubuf, zb, rbuf, hx, nullptr);
  // 9. q,k from z
  k_qkprep<<<dim3(1024), dim3(256), 0, stream>>>(zb, qk_gamma, qk_beta, qb, kb2, BL * Z_);
  // 10. fused QK+softmax -> packed P (all 8 batches, one dispatch)
  k_qksm<<<dim3(NTILE_, B_), dim3(256), 0, stream>>>(qb, kb2, rel_bias, Ppack);
  // 11. PV GEMM, hr = (P@V)*r in-place over rbuf (one dispatch)
  k_pv<<<dim3(NTILE_, H_ / 128, B_), dim3(256), 0, stream>>>(Ppack, vT, rbuf);
  // 12. Wh -> bf16 (over dead wmx_b)
  k_f2bf<<<dim3(1024), dim3(256), 0, stream>>>(Wh, wh_b, D_ * H_);
  // 13. final: g = silu(hx + hr@Wh^T); out = x + u*(g-x)
  k_gemm128<4><<<dim3(BL / 128, D_ / 128), dim3(256), 0, stream>>>(
      rbuf, wh_b, D_, H_, nullptr, out, nullptr,
      ubuf, nullptr, nullptr, hx, x);
}

// Round 8
// 1153.146 us; speedup vs baseline: 1.2669x; 1.0039x over previous
//
#include <hip/hip_runtime.h>
#include <stdint.h>

#define B_ 8
#define L_ 2048
#define D_ 1024
#define Z_ 128
#define H_ 2048
#define NE_ 16
#define G_ 32
#define MAXPOS_ 2048
#define NMX_ 4224   // D + Z + H + D (u | z | r | hx) = 33 * 128 exactly
#define EPS_ 1e-5f
#define PC_ 2.0f
#define NTILE_ 16            // L/128 q-tiles
#define NPACK_ 136           // 16*17/2 packed causal tiles
#define TILE_ELEMS_ 16384    // 128*128

typedef short bf16x8 __attribute__((ext_vector_type(8)));
typedef float f32x4 __attribute__((ext_vector_type(4)));

__device__ __forceinline__ float bf2f(uint16_t u) {
  union { uint32_t u; float f; } v; v.u = ((uint32_t)u) << 16; return v.f;
}
__device__ __forceinline__ uint16_t f2bf(float f) {
  union { float f; uint32_t u; } v; v.f = f;
  uint32_t r = (v.u + 0x7FFFu + ((v.u >> 16) & 1u)) >> 16;
  return (uint16_t)r;
}
__device__ __forceinline__ float sigmoidf_(float x) { return 1.f / (1.f + __expf(-x)); }
__device__ __forceinline__ float siluf_(float x) { return x / (1.f + __expf(-x)); }

__device__ __forceinline__ float waveRedSum(float v) {
  #pragma unroll
  for (int m = 32; m; m >>= 1) v += __shfl_xor(v, m, 64);
  return v;
}

// async global->LDS, 16 bytes per lane; lds dst must be waveBase + lane*16
__device__ __forceinline__ void gl2lds(const uint16_t* g, uint16_t* l) {
  __builtin_amdgcn_global_load_lds(
      (const __attribute__((address_space(1))) void*)g,
      (__attribute__((address_space(3))) void*)l, 16, 0, 0);
}

// ---------------- fallback when workspace too small ----------------
__global__ __launch_bounds__(256) void k_fallback(float* __restrict__ out, int n, float wsmb) {
  for (int i = blockIdx.x * 256 + threadIdx.x; i < n; i += gridDim.x * 256)
    out[i] = (i == 0) ? wsmb : 0.f;
}

// ---------------- fp32 -> bf16 conversion (weights) ----------------
__global__ __launch_bounds__(256) void k_f2bf(const float* __restrict__ src,
                                              uint16_t* __restrict__ dst, int n) {
  for (int i = blockIdx.x * 256 + threadIdx.x; i < n; i += gridDim.x * 256)
    dst[i] = f2bf(src[i]);
}

// ---------------- TimestepNorm, parallel 3-phase ----------------
__global__ __launch_bounds__(256) void k_tnsum(const float* __restrict__ x,
                                               float* __restrict__ s1g,
                                               float* __restrict__ s2g) {
  const int bg = blockIdx.x;
  const int b = bg / G_, g = bg % G_;
  const int tid = threadIdx.x;
  const int j = tid & 31;
  const int lsub = tid >> 5;
  #pragma unroll
  for (int i = 0; i < 16; ++i) {
    const int l = blockIdx.y * 128 + i * 8 + lsub;
    float v = x[((size_t)(b * L_ + l)) * D_ + g * 32 + j];
    float a = v, sq = v * v;
    #pragma unroll
    for (int m = 1; m <= 16; m <<= 1) { a += __shfl_xor(a, m, 64); sq += __shfl_xor(sq, m, 64); }
    if (j == 0) { s1g[(size_t)bg * L_ + l] = a; s2g[(size_t)bg * L_ + l] = sq; }
  }
}

__global__ __launch_bounds__(64) void k_tnscan(float* __restrict__ s1g,
                                               float* __restrict__ s2g) {
  const int bg = blockIdx.x;
  const int lane = threadIdx.x;
  #pragma unroll
  for (int pass = 0; pass < 2; ++pass) {
    float* gp = (pass ? s2g : s1g) + (size_t)bg * L_;
    float loc[32];
    const int b0 = lane * 32;
    float tot = 0.f;
    #pragma unroll
    for (int t = 0; t < 32; ++t) { loc[t] = gp[b0 + t]; tot += loc[t]; }
    float incl = tot;
    #pragma unroll
    for (int off = 1; off < 64; off <<= 1) {
      float nv = __shfl_up(incl, off, 64);
      if (lane >= off) incl += nv;
    }
    float run = incl - tot;
    #pragma unroll
    for (int t = 0; t < 32; ++t) { run += loc[t]; gp[b0 + t] = run; }
  }
}

__global__ __launch_bounds__(256) void k_tnnorm(const float* __restrict__ x,
                                                const float* __restrict__ s1g,
                                                const float* __restrict__ s2g,
                                                const float* __restrict__ pm,
                                                const float* __restrict__ plv,
                                                const float* __restrict__ w,
                                                const float* __restrict__ bias,
                                                uint16_t* __restrict__ xn) {
  const int bg = blockIdx.x;
  const int b = bg / G_, g = bg % G_;
  const int tid = threadIdx.x;
  const int j = tid & 31;
  const int lsub = tid >> 5;
  const float pmv = pm[g];
  const float pvv = __expf(plv[g]);
  const float wj = w[g * 32 + j];
  const float bj = bias[g * 32 + j];
  const float pterm = PC_ * (pvv + pmv * pmv);
  #pragma unroll
  for (int i = 0; i < 16; ++i) {
    const int l = blockIdx.y * 128 + i * 8 + lsub;
    const size_t idx = ((size_t)(b * L_ + l)) * D_ + g * 32 + j;
    const float v = x[idx];
    const float cnt = PC_ + 32.f * (float)(l + 1);
    const float mean = (PC_ * pmv + s1g[(size_t)bg * L_ + l]) / cnt;
    const float var = (pterm + s2g[(size_t)bg * L_ + l]) / cnt - mean * mean;
    xn[idx] = f2bf((v - mean) * rsqrtf(var + EPS_) * wj + bj);
  }
}

// ---------------- vectorized 64x64-tile transposes ----------------
__global__ __launch_bounds__(256) void k_tp16(const uint16_t* __restrict__ src,
                                              uint16_t* __restrict__ dst, int R, int C) {
  __shared__ uint16_t tile[64 * 65];
  const size_t batch = (size_t)R * C * blockIdx.z;
  const int c0 = blockIdx.x * 64, r0 = blockIdx.y * 64;
  const int t = threadIdx.x;
  const int rr = t >> 3;          // 0..31
  const int cc = (t & 7) * 8;     // 0,8,..,56
  #pragma unroll
  for (int p = 0; p < 2; ++p) {
    const int row = p * 32 + rr;
    bf16x8 v = *(const bf16x8*)&src[batch + (size_t)(r0 + row) * C + c0 + cc];
    #pragma unroll
    for (int i = 0; i < 8; ++i) tile[(cc + i) * 65 + row] = (uint16_t)v[i];
  }
  __syncthreads();
  #pragma unroll
  for (int p = 0; p < 2; ++p) {
    const int crow = p * 32 + rr;
    bf16x8 o;
    #pragma unroll
    for (int i = 0; i < 8; ++i) o[i] = (short)tile[crow * 65 + cc + i];
    *(bf16x8*)&dst[batch + (size_t)(c0 + crow) * R + r0 + cc] = o;
  }
}

__global__ __launch_bounds__(256) void k_tpf32(const float* __restrict__ src,
                                               float* __restrict__ dst, int R, int C) {
  __shared__ float tile[64 * 65];
  const size_t batch = (size_t)R * C * blockIdx.z;
  const int c0 = blockIdx.x * 64, r0 = blockIdx.y * 64;
  const int t = threadIdx.x;
  const int rr = t >> 4;          // 0..15
  const int cc = (t & 15) * 4;    // 0..60
  #pragma unroll
  for (int p = 0; p < 4; ++p) {
    const int row = p * 16 + rr;
    f32x4 v = *(const f32x4*)&src[batch + (size_t)(r0 + row) * C + c0 + cc];
    #pragma unroll
    for (int i = 0; i < 4; ++i) tile[(cc + i) * 65 + row] = v[i];
  }
  __syncthreads();
  #pragma unroll
  for (int p = 0; p < 4; ++p) {
    const int crow = p * 16 + rr;
    f32x4 o;
    #pragma unroll
    for (int i = 0; i < 4; ++i) o[i] = tile[crow * 65 + cc + i];
    *(f32x4*)&dst[batch + (size_t)(c0 + crow) * R + r0 + cc] = o;
  }
}

// ---------------- MultiHeadEMA via chunked linear recurrence ----------------
__global__ __launch_bounds__(64) void k_ema(const uint16_t* __restrict__ xnT,
                                            const float* __restrict__ delta,
                                            const float* __restrict__ alpha,
                                            const float* __restrict__ beta,
                                            const float* __restrict__ gamma,
                                            const float* __restrict__ omega,
                                            float* __restrict__ mxT) {
  __shared__ float hst[64 * NE_];
  const int bd = blockIdx.x;
  const int d = bd & (D_ - 1);
  const int c = threadIdx.x;

  float q[NE_], pb[NE_], gs[NE_];
  #pragma unroll
  for (int n = 0; n < NE_; ++n) {
    float p = sigmoidf_(delta[d * NE_ + n]);
    float a = sigmoidf_(alpha[d * NE_ + n]);
    q[n] = 1.f - p * a;
    pb[n] = p * beta[d * NE_ + n];
    gs[n] = gamma[d * NE_ + n] * 0.25f;
  }

  const uint16_t* xp = xnT + (size_t)bd * L_ + c * 32;
  bf16x8 xin[4];
  #pragma unroll
  for (int s = 0; s < 4; ++s) xin[s] = *(const bf16x8*)(xp + s * 8);

  float h[NE_];
  #pragma unroll
  for (int n = 0; n < NE_; ++n) h[n] = 0.f;

  #pragma unroll
  for (int k = 0; k < 32; ++k) {
    float xv = bf2f((uint16_t)xin[k >> 3][k & 7]);
    #pragma unroll
    for (int n = 0; n < NE_; ++n) h[n] = fmaf(q[n], h[n], pb[n] * xv);
  }
  #pragma unroll
  for (int n = 0; n < NE_; ++n) hst[c * NE_ + n] = h[n];
  __syncthreads();

  if (c < NE_) {
    float qq = q[c];
    float q32 = qq * qq; q32 *= q32; q32 *= q32; q32 *= q32; q32 *= q32;  // q^32
    float hi = 0.f;
    for (int cc = 0; cc < 64; ++cc) {
      float cur = hst[cc * NE_ + c];
      hst[cc * NE_ + c] = hi;
      hi = fmaf(q32, hi, cur);
    }
  }
  __syncthreads();

  #pragma unroll
  for (int n = 0; n < NE_; ++n) h[n] = hst[c * NE_ + n];
  const float om = omega[d];
  float* op = mxT + (size_t)bd * L_ + c * 32;
  f32x4 ov;
  #pragma unroll
  for (int k = 0; k < 32; ++k) {
    float xv = bf2f((uint16_t)xin[k >> 3][k & 7]);
    float accv = 0.f;
    #pragma unroll
    for (int n = 0; n < NE_; ++n) {
      h[n] = fmaf(q[n], h[n], pb[n] * xv);
      accv = fmaf(gs[n], h[n], accv);
    }
    ov[k & 3] = accv + om * xv;
    if ((k & 3) == 3) *(f32x4*)(op + (k & ~3)) = ov;
  }
}

// ---------------- RMS norm over D ----------------
__global__ __launch_bounds__(256) void k_rms(const float* __restrict__ mx,
                                             const float* __restrict__ w,
                                             uint16_t* __restrict__ mxn) {
  __shared__ float red[4];
  const size_t row = blockIdx.x;
  const int tid = threadIdx.x;
  float ss = 0.f;
  #pragma unroll
  for (int i = 0; i < 4; ++i) {
    float v = mx[row * D_ + tid + i * 256];
    ss += v * v;
  }
  ss = waveRedSum(ss);
  if ((tid & 63) == 0) red[tid >> 6] = ss;
  __syncthreads();
  ss = red[0] + red[1] + red[2] + red[3];
  const float scale = rsqrtf(ss * (1.f / D_) + EPS_);
  #pragma unroll
  for (int i = 0; i < 4; ++i) {
    int dcol = tid + i * 256;
    mxn[row * D_ + dcol] = f2bf(mx[row * D_ + dcol] * scale * w[dcol]);
  }
}

// ==================================================================
// 128x128-tile, BK=32, 4-wave, 2-phase prefetch GEMM, 4 blocks/CU.
// (round-6/7 structure, ~606 TF on BASE — at the 2-phase plateau)
//
// Round-8: MODE 1's z-branch now computes q,k directly (fuses the old
// k_qkprep kernel; zb buffer eliminated; numerically identical).
//
// C = A(MxK) @ B(NxK)^T, fused epilogues:
//  MODE 0: V     vT[b][h][l] = silu(acc + bv[h])         (transposed)
//  MODE 1: BASE  acc + bmx[col], split u/(q,k)/r/hx
//  MODE 4: WH    g=silu(acc+hx); out = x + u*(g-x)        -> f32 d_out
// ==================================================================

template <int MODE>
__global__ __launch_bounds__(256, 4) void k_gemm128(
    const uint16_t* __restrict__ A, const uint16_t* __restrict__ Bm,
    int N, int K,
    const float* __restrict__ bias,
    float* __restrict__ outf, uint16_t* __restrict__ outb,
    uint16_t* __restrict__ ubuf,
    uint16_t* __restrict__ rbuf, float* __restrict__ hxbuf,
    const float* __restrict__ x0,
    const float* __restrict__ qkg, const float* __restrict__ qkb,
    uint16_t* __restrict__ qbuf, uint16_t* __restrict__ kbuf) {
  __shared__ uint16_t sm[17408];  // 34.8 KiB: dbuf at 0/8192; MODE0 epi reuses all
  const int t = threadIdx.x;
  const int lane = t & 63, wave = t >> 6;
  const int quad = lane >> 4, r16 = lane & 15;
  const int wm = wave >> 1, wn = wave & 1;
  const int bm = blockIdx.x * 128;
  const int bn = blockIdx.y * 128;

  f32x4 acc[4][4];
  const f32x4 zf = {0.f, 0.f, 0.f, 0.f};
  #pragma unroll
  for (int i = 0; i < 4; ++i)
    #pragma unroll
    for (int j = 0; j < 4; ++j) acc[i][j] = zf;

  // staging: thread t -> rows {t>>2, 64+(t>>2)}, phys granule t&3;
  // LDS dest linear; global col pre-swizzled: logical = (t&3)^((t>>3)&3)
  const int sgz = (((t & 3) ^ ((t >> 3) & 3)) << 3);
  const uint16_t* gA = A + (size_t)(bm + (t >> 2)) * K + sgz;
  const uint16_t* gB = Bm + (size_t)(bn + (t >> 2)) * K + sgz;
  const size_t qstep = (size_t)64 * K;
  uint16_t* lA = sm + t * 8;
  uint16_t* lB = sm + 4096 + t * 8;

  // reads: row*32 + ((quad ^ ((row>>1)&3))<<3)
  const int ga = ((quad ^ ((r16 >> 1) & 3)) << 3);
  const int aOff = (wm * 64 + r16) * 32 + ga;
  const int bOff = 4096 + (wn * 64 + r16) * 32 + ga;

#define STAGE(c, kb) do {                                                     \
    gl2lds(gA + (kb), lA + (c) * 8192);                                       \
    gl2lds(gA + qstep + (kb), lA + (c) * 8192 + 2048);                        \
    gl2lds(gB + (kb), lB + (c) * 8192);                                       \
    gl2lds(gB + qstep + (kb), lB + (c) * 8192 + 2048);                        \
  } while (0)

  const int NT = K >> 5;

  STAGE(0, 0);
  __syncthreads();  // vmcnt(0) drain + barrier

  bf16x8 af[4], bfr[4];
  for (int tt = 0; tt < NT; ++tt) {
    const int c = tt & 1;
    const int co = c * 8192;
    if (tt + 1 < NT) STAGE(c ^ 1, (tt + 1) * 32);  // prefetch next tile
    #pragma unroll
    for (int j = 0; j < 4; ++j)
      bfr[j] = *(const bf16x8*)&sm[co + bOff + j * 512];
    #pragma unroll
    for (int i = 0; i < 4; ++i)
      af[i] = *(const bf16x8*)&sm[co + aOff + i * 512];
    #pragma unroll
    for (int i = 0; i < 4; ++i)
      #pragma unroll
      for (int j = 0; j < 4; ++j)
        acc[i][j] = __builtin_amdgcn_mfma_f32_16x16x32_bf16(
            af[i], bfr[j], acc[i][j], 0, 0, 0);
    __syncthreads();  // single vmcnt(0)+barrier per K-tile
  }
#undef STAGE

  // ---- epilogue ----
  if (MODE == 0) {
    // silu+bias, store transposed into sm[h][l] (row stride 136), then
    // coalesced 16B writes to vT[b][h][l].
    #pragma unroll
    for (int i = 0; i < 4; ++i)
      #pragma unroll
      for (int j = 0; j < 4; ++j)
        #pragma unroll
        for (int r = 0; r < 4; ++r) {
          const int hloc = wn * 64 + j * 16 + r16;
          const int lloc = wm * 64 + i * 16 + quad * 4 + r;
          sm[hloc * 136 + lloc] = f2bf(siluf_(acc[i][j][r] + bias[bn + hloc]));
        }
    __syncthreads();
    const int bb = bm >> 11;            // batch index (tile never crosses)
    const int lb = bm & 2047;           // l offset within batch
    uint16_t* vTb = outb + (size_t)bb * H_ * L_;
    #pragma unroll
    for (int p = 0; p < 8; ++p) {
      const int hloc = p * 16 + (t >> 4);
      const int l0 = (t & 15) * 8;
      bf16x8 v = *(const bf16x8*)&sm[hloc * 136 + l0];
      *(bf16x8*)&vTb[(size_t)(bn + hloc) * L_ + lb + l0] = v;
    }
  } else {
    #pragma unroll
    for (int i = 0; i < 4; ++i) {
      #pragma unroll
      for (int j = 0; j < 4; ++j) {
        #pragma unroll
        for (int r = 0; r < 4; ++r) {
          const int row = bm + wm * 64 + i * 16 + quad * 4 + r;
          const int col = bn + wn * 64 + j * 16 + r16;
          float val = acc[i][j][r];
          if (MODE == 1) {
            val += bias[col];
            if (col < D_) {
              ubuf[(size_t)row * D_ + col] = f2bf(sigmoidf_(val));
            } else if (col < D_ + Z_) {
              const int zc = col - D_;
              const float zv = siluf_(val);
              qbuf[(size_t)row * Z_ + zc] =
                  f2bf((zv * qkg[zc] + qkb[zc]) * 0.08838834764831845f);
              kbuf[(size_t)row * Z_ + zc] =
                  f2bf(zv * qkg[Z_ + zc] + qkb[Z_ + zc]);
            } else if (col < D_ + Z_ + H_) {
              rbuf[(size_t)row * H_ + (col - D_ - Z_)] = f2bf(siluf_(val));
            } else {
              hxbuf[(size_t)row * D_ + (col - D_ - Z_ - H_)] = val;
            }
          } else {
            const size_t idx = (size_t)row * N + col;
            float g = siluf_(val + hxbuf[idx]);   // read hx (d_out) ...
            float xv = x0[idx];
            outf[idx] = xv + bf2f(ubuf[idx]) * (g - xv);  // ... then write same addr
          }
        }
      }
    }
  }
}

// ---- fused QK^T + rel_bias + causal softmax -> packed-triangular P (bf16) ----
// Round-8: K/relwin staging double-buffered with prefetch (1 barrier/kt,
// drain off the critical path — the 128-block grid is latency-bound on
// its longest block).  Granule XOR-swizzle unchanged.
__global__ __launch_bounds__(256) void k_qksm(
    const uint16_t* __restrict__ qg, const uint16_t* __restrict__ kg,
    const float* __restrict__ relb, uint16_t* __restrict__ Pp) {
  __shared__ uint16_t Ks[2 * 16384];
  __shared__ float relwin[2 * 256];
  const int qt = blockIdx.x;
  const int bl = blockIdx.y;
  const int tid = threadIdx.x;
  const int w = tid >> 6, lane = tid & 63;
  const int quad = lane >> 4, r16 = lane & 15;
  const uint16_t* qb_b = qg + (size_t)bl * L_ * Z_;
  const uint16_t* kb_b = kg + (size_t)bl * L_ * Z_;
  uint16_t* P_b = Pp + (size_t)bl * NPACK_ * TILE_ELEMS_;

  const int ksg = (tid >> 4) * 128 + (((tid & 15) ^ ((tid >> 4) & 7)) << 3);
  const int kg7 = r16 & 7;

#define STGK(c, kt) do {                                                      \
    const uint16_t* src_ = kb_b + (size_t)(kt) * 128 * Z_;                    \
    _Pragma("unroll")                                                         \
    for (int s2 = 0; s2 < 8; ++s2)                                            \
      gl2lds(src_ + s2 * 2048 + ksg, Ks + (c) * 16384 + s2 * 2048 + tid * 8); \
    if (tid < 255)                                                            \
      relwin[(c) * 256 + tid] = relb[2047 + ((kt) - qt) * 128 - 127 + tid];   \
  } while (0)

  bf16x8 aq[2][4];
  #pragma unroll
  for (int i = 0; i < 2; ++i)
    #pragma unroll
    for (int s = 0; s < 4; ++s)
      aq[i][s] = *(const bf16x8*)&qb_b[(size_t)(qt * 128 + w * 32 + i * 16 + r16) * Z_ +
                                       s * 32 + quad * 8];

  float m8[8], l8[8];
  #pragma unroll
  for (int t = 0; t < 8; ++t) { m8[t] = -3.4e38f; l8[t] = 0.f; }

  const f32x4 zf = {0.f, 0.f, 0.f, 0.f};

  // ---- phase 1: stats ----
  STGK(0, 0);
  __syncthreads();
  for (int kt = 0; kt <= qt; ++kt) {
    const int cur = kt & 1;
    if (kt < qt) STGK(cur ^ 1, kt + 1);
    const uint16_t* Kc = Ks + cur * 16384;
    const float* rw = relwin + cur * 256;
    #pragma unroll
    for (int j = 0; j < 8; ++j) {
      f32x4 a0 = zf, a1 = zf;
      #pragma unroll
      for (int s = 0; s < 4; ++s) {
        bf16x8 bk = *(const bf16x8*)&Kc[(j * 16 + r16) * 128 +
                                        (((s * 4 + quad) ^ kg7) << 3)];
        a0 = __builtin_amdgcn_mfma_f32_16x16x32_bf16(aq[0][s], bk, a0, 0, 0, 0);
        a1 = __builtin_amdgcn_mfma_f32_16x16x32_bf16(aq[1][s], bk, a1, 0, 0, 0);
      }
      #pragma unroll
      for (int i = 0; i < 2; ++i) {
        const f32x4 av = i ? a1 : a0;
        #pragma unroll
        for (int r = 0; r < 4; ++r) {
          const int rloc = w * 32 + i * 16 + quad * 4 + r;
          const int cloc = j * 16 + r16;
          if (kt < qt || cloc <= rloc) {
            const float v = av[r] + rw[cloc - rloc + 127];
            const int t = i * 4 + r;
            const float mn = fmaxf(m8[t], v);
            l8[t] = l8[t] * __expf(m8[t] - mn) + __expf(v - mn);
            m8[t] = mn;
          }
        }
      }
    }
    __syncthreads();
  }

  #pragma unroll
  for (int t = 0; t < 8; ++t) {
    #pragma unroll
    for (int msk = 1; msk <= 8; msk <<= 1) {
      const float mo = __shfl_xor(m8[t], msk, 64);
      const float lo = __shfl_xor(l8[t], msk, 64);
      const float mn = fmaxf(m8[t], mo);
      l8[t] = l8[t] * __expf(m8[t] - mn) + lo * __expf(mo - mn);
      m8[t] = mn;
    }
    l8[t] = 1.f / l8[t];
  }

  // ---- phase 2: recompute, normalize, write packed P ----
  STGK(0, 0);
  __syncthreads();
  for (int kt = 0; kt <= qt; ++kt) {
    const int cur = kt & 1;
    if (kt < qt) STGK(cur ^ 1, kt + 1);
    const uint16_t* Kc = Ks + cur * 16384;
    const float* rw = relwin + cur * 256;
    uint16_t* Pt = P_b + (size_t)(qt * (qt + 1) / 2 + kt) * TILE_ELEMS_;
    #pragma unroll
    for (int j = 0; j < 8; ++j) {
      f32x4 a0 = zf, a1 = zf;
      #pragma unroll
      for (int s = 0; s < 4; ++s) {
        bf16x8 bk = *(const bf16x8*)&Kc[(j * 16 + r16) * 128 +
                                        (((s * 4 + quad) ^ kg7) << 3)];
        a0 = __builtin_amdgcn_mfma_f32_16x16x32_bf16(aq[0][s], bk, a0, 0, 0, 0);
        a1 = __builtin_amdgcn_mfma_f32_16x16x32_bf16(aq[1][s], bk, a1, 0, 0, 0);
      }
      #pragma unroll
      for (int i = 0; i < 2; ++i) {
        const f32x4 av = i ? a1 : a0;
        #pragma unroll
        for (int r = 0; r < 4; ++r) {
          const int rloc = w * 32 + i * 16 + quad * 4 + r;
          const int cloc = j * 16 + r16;
          const int t = i * 4 + r;
          float p = 0.f;
          if (kt < qt || cloc <= rloc) {
            const float v = av[r] + rw[cloc - rloc + 127];
            p = __expf(v - m8[t]) * l8[t];
          }
          Pt[rloc * 128 + cloc] = f2bf(p);
        }
      }
    }
    __syncthreads();
  }
#undef STGK
}

// ---- PV GEMM: hr = (P @ V) * r, packed-triangular P, in-place over r ----
// Round-8: 128x256 tile, 8 waves (512 thr), halves P re-reads (8 bn-blocks
// instead of 16) and block count.  BK=32 dbuf prefetch (1 barrier/step),
// LDS 48 KiB, (512,4) -> VGPR cap 128 (no spill), 2 blocks/CU.
// Swizzle: phys granule = logical ^ ((row>>1)&3) (2-way free on [*][32]).
// Grid reversed so heavy (large qt) blocks launch first.
__global__ __launch_bounds__(512, 4) void k_pv(
    const uint16_t* __restrict__ Pp, const uint16_t* __restrict__ vT,
    uint16_t* __restrict__ rh) {
  __shared__ uint16_t sm[24576];  // 48 KiB: buf c at c*12288; A(4096) +0, B(8192) +4096
  const int qt = NTILE_ - 1 - blockIdx.x;   // heavy blocks first
  const int bn = blockIdx.y * 256;
  const int bl = blockIdx.z;
  const uint16_t* Pq = Pp + (size_t)bl * NPACK_ * TILE_ELEMS_ +
                       (size_t)(qt * (qt + 1) / 2) * TILE_ELEMS_;
  const uint16_t* v_b = vT + (size_t)bl * H_ * L_;
  uint16_t* rh_b = rh + (size_t)bl * L_ * H_;

  const int tid = threadIdx.x;
  const int wave = tid >> 6, lane = tid & 63;
  const int quad = lane >> 4, r16 = lane & 15;
  const int wm = wave >> 2, wn = wave & 3;
  const int rowW = wm * 64, colW = wn * 64;

  f32x4 acc[4][4];
  const f32x4 zf = {0.f, 0.f, 0.f, 0.f};
  #pragma unroll
  for (int i = 0; i < 4; ++i)
    #pragma unroll
    for (int j = 0; j < 4; ++j) acc[i][j] = zf;

  const int rA = tid >> 2;   // 0..127
  // staging: phys granule tid&3 -> logical (tid&3)^((rA>>1)&3)
  const int sg = (((tid & 3) ^ ((tid >> 3) & 3)) << 3);
  // reads: phys granule = quad ^ ((row>>1)&3)
  const int gpv = ((quad ^ ((r16 >> 1) & 3)) << 3);

#define PVSTAGE(c, s) do {                                                    \
    const int kt_ = (s) >> 2, ks_ = (s) & 3;                                  \
    gl2lds(Pq + (size_t)kt_ * TILE_ELEMS_ + rA * 128 + ks_ * 32 + sg,         \
           sm + (c) * 12288 + tid * 8);                                       \
    const uint16_t* Bt_ = v_b + (size_t)(bn + rA) * L_ + kt_ * 128 +          \
                          ks_ * 32 + sg;                                      \
    gl2lds(Bt_, sm + (c) * 12288 + 4096 + tid * 8);                           \
    gl2lds(Bt_ + (size_t)128 * L_, sm + (c) * 12288 + 8192 + tid * 8);        \
  } while (0)

  const int S = 4 * (qt + 1);

  PVSTAGE(0, 0);
  __syncthreads();

  bf16x8 af[4], bfr[4];
  for (int s = 0; s < S; ++s) {
    const int c = s & 1;
    const int co = c * 12288;
    if (s + 1 < S) PVSTAGE(c ^ 1, s + 1);
    #pragma unroll
    for (int j = 0; j < 4; ++j)
      bfr[j] = *(const bf16x8*)&sm[co + 4096 + (colW + j * 16 + r16) * 32 + gpv];
    #pragma unroll
    for (int i = 0; i < 4; ++i)
      af[i] = *(const bf16x8*)&sm[co + (rowW + i * 16 + r16) * 32 + gpv];
    #pragma unroll
    for (int i = 0; i < 4; ++i)
      #pragma unroll
      for (int j = 0; j < 4; ++j)
        acc[i][j] = __builtin_amdgcn_mfma_f32_16x16x32_bf16(af[i], bfr[j], acc[i][j], 0, 0, 0);
    __syncthreads();
  }
#undef PVSTAGE

  #pragma unroll
  for (int i = 0; i < 4; ++i) {
    #pragma unroll
    for (int j = 0; j < 4; ++j) {
      #pragma unroll
      for (int r = 0; r < 4; ++r) {
        const int row = qt * 128 + rowW + i * 16 + quad * 4 + r;
        const int col = bn + colW + j * 16 + r16;
        const size_t idx = (size_t)row * H_ + col;
        const float rv = bf2f(rh_b[idx]);
        rh_b[idx] = f2bf(acc[i][j][r] * rv);
      }
    }
  }
}

extern "C" void kernel_launch(void* const* d_in, const int* in_sizes, int n_in,
                              void* d_out, int out_size, void* d_ws, size_t ws_size,
                              hipStream_t stream) {
  (void)in_sizes; (void)n_in;
  const float* x         = (const float*)d_in[0];
  const float* prior_mean= (const float*)d_in[1];
  const float* prior_logv= (const float*)d_in[2];
  const float* tn_w      = (const float*)d_in[3];
  const float* tn_b      = (const float*)d_in[4];
  const float* delta     = (const float*)d_in[5];
  const float* alpha     = (const float*)d_in[6];
  const float* ema_beta  = (const float*)d_in[7];
  const float* ema_gamma = (const float*)d_in[8];
  const float* omega     = (const float*)d_in[9];
  const float* rms_w     = (const float*)d_in[10];
  const float* Wv        = (const float*)d_in[11];
  const float* bv        = (const float*)d_in[12];
  const float* Wmx       = (const float*)d_in[13];
  const float* bmx       = (const float*)d_in[14];
  const float* Wh        = (const float*)d_in[15];
  const float* qk_gamma  = (const float*)d_in[16];
  const float* qk_beta   = (const float*)d_in[17];
  const float* rel_bias  = (const float*)d_in[18];
  float* out = (float*)d_out;

  const int BL = B_ * L_;
  const size_t MB = 1024 * 1024;
  const size_t REQUIRED = 256 * MB;

  if (ws_size < REQUIRED) {
    k_fallback<<<dim3(4096), dim3(256), 0, stream>>>(out, out_size, (float)(ws_size / MB));
    return;
  }

  char* p = (char*)d_ws;
  // A [0,32): xn (bf16) -> ubuf (bf16)
  uint16_t* xn   = (uint16_t*)(p);
  uint16_t* ubuf = (uint16_t*)(p);
  // B [32,64): s1s2 (4MB, tnorm only) -> xnT -> mxn
  float*    s1g  = (float*)   (p + 32 * MB);
  float*    s2g  = (float*)   (p + 34 * MB);
  uint16_t* xnT  = (uint16_t*)(p + 32 * MB);
  uint16_t* mxn  = (uint16_t*)(p + 32 * MB);
  // C [64,128): vT (64 MiB exactly; written by V GEMM, read by k_pv)
  uint16_t* vT   = (uint16_t*)(p + 64 * MB);
  // D [128,192): wv_b (steps 1-4) -> mx f32 (6-7) -> rbuf/hr (8-13)
  uint16_t* wv_b = (uint16_t*)(p + 128 * MB);
  float*    mx   = (float*)   (p + 128 * MB);
  uint16_t* rbuf = (uint16_t*)(p + 128 * MB);
  // E [192,256): wmx_b(8.25) | qb(4) | kb(4) | Ppack(35.65)
  uint16_t* wmx_b = (uint16_t*)(p + 192 * MB);
  uint16_t* wh_b  = (uint16_t*)(p + 192 * MB);
  uint16_t* qb    = (uint16_t*)(p + 209 * MB);
  uint16_t* kb2   = (uint16_t*)(p + 213 * MB);
  uint16_t* Ppack = (uint16_t*)(p + 217 * MB);
  // d_out doubles as: mxT f32 (EMA out) -> hx f32 (BASE out) -> out
  float* mxT = out;
  float* hx  = out;

  // 1. weights -> bf16
  k_f2bf<<<dim3(1024), dim3(256), 0, stream>>>(Wv, wv_b, H_ * D_);
  k_f2bf<<<dim3(2048), dim3(256), 0, stream>>>(Wmx, wmx_b, NMX_ * D_);
  // 2. timestep norm (3-phase parallel) -> xn
  k_tnsum<<<dim3(B_ * G_, 16), dim3(256), 0, stream>>>(x, s1g, s2g);
  k_tnscan<<<dim3(B_ * G_), dim3(64), 0, stream>>>(s1g, s2g);
  k_tnnorm<<<dim3(B_ * G_, 16), dim3(256), 0, stream>>>(
      x, s1g, s2g, prior_mean, prior_logv, tn_w, tn_b, xn);
  // 3. xn -> xnT (vectorized 64x64 transpose; overwrites dead s1s2)
  k_tp16<<<dim3(D_ / 64, L_ / 64, B_), dim3(256), 0, stream>>>(xn, xnT, L_, D_);
  // 4. v = silu(xn @ Wv^T + bv), written TRANSPOSED -> vT (C)
  k_gemm128<0><<<dim3(BL / 128, H_ / 128), dim3(256), 0, stream>>>(
      xn, wv_b, H_, D_, bv, nullptr, vT,
      nullptr, nullptr, nullptr, nullptr, nullptr, nullptr, nullptr, nullptr);
  // 5. EMA: xnT -> mxT (d_out)
  k_ema<<<dim3(B_ * D_), dim3(64), 0, stream>>>(xnT, delta, alpha, ema_beta, ema_gamma, omega, mxT);
  // 6. mxT -> mx (vectorized f32 transpose; overwrites dead wv_b)
  k_tpf32<<<dim3(L_ / 64, D_ / 64, B_), dim3(256), 0, stream>>>(mxT, mx, D_, L_);
  // 7. RMS norm -> mxn (overwrites dead xnT)
  k_rms<<<dim3(BL), dim3(256), 0, stream>>>(mx, rms_w, mxn);
  // 8. BASE GEMM -> u(A), q/k(E, fused qkprep), r(D), hx(d_out)
  k_gemm128<1><<<dim3(BL / 128, NMX_ / 128), dim3(256), 0, stream>>>(
      mxn, wmx_b, NMX_, D_, bmx, nullptr, nullptr,
      ubuf, rbuf, hx, nullptr, qk_gamma, qk_beta, qb, kb2);
  // 9. fused QK+softmax -> packed P (all 8 batches, one dispatch)
  k_qksm<<<dim3(NTILE_, B_), dim3(256), 0, stream>>>(qb, kb2, rel_bias, Ppack);
  // 10. PV GEMM, hr = (P@V)*r in-place over rbuf (one dispatch)
  k_pv<<<dim3(NTILE_, H_ / 256, B_), dim3(512), 0, stream>>>(Ppack, vT, rbuf);
  // 11. Wh -> bf16 (over dead wmx_b)
  k_f2bf<<<dim3(1024), dim3(256), 0, stream>>>(Wh, wh_b, D_ * H_);
  // 12. final: g = silu(hx + hr@Wh^T); out = x + u*(g-x)
  k_gemm128<4><<<dim3(BL / 128, D_ / 128), dim3(256), 0, stream>>>(
      rbuf, wh_b, D_, H_, nullptr, out, nullptr,
      ubuf, nullptr, hx, x, nullptr, nullptr, nullptr, nullptr);
}

// Round 10
// 1109.280 us; speedup vs baseline: 1.3170x; 1.0395x over previous
//
#include <hip/hip_runtime.h>
#include <stdint.h>

#define B_ 8
#define L_ 2048
#define D_ 1024
#define Z_ 128
#define H_ 2048
#define NE_ 16
#define G_ 32
#define MAXPOS_ 2048
#define NMX_ 4224   // D + Z + H + D (u | z | r | hx) = 33 * 128 exactly
#define EPS_ 1e-5f
#define PC_ 2.0f
#define NTILE_ 16            // L/128 q-tiles
#define NPACK_ 136           // 16*17/2 packed causal tiles
#define TILE_ELEMS_ 16384    // 128*128

typedef short bf16x8 __attribute__((ext_vector_type(8)));
typedef float f32x4 __attribute__((ext_vector_type(4)));

__device__ __forceinline__ float bf2f(uint16_t u) {
  union { uint32_t u; float f; } v; v.u = ((uint32_t)u) << 16; return v.f;
}
__device__ __forceinline__ uint16_t f2bf(float f) {
  union { float f; uint32_t u; } v; v.f = f;
  uint32_t r = (v.u + 0x7FFFu + ((v.u >> 16) & 1u)) >> 16;
  return (uint16_t)r;
}
__device__ __forceinline__ float sigmoidf_(float x) { return 1.f / (1.f + __expf(-x)); }
__device__ __forceinline__ float siluf_(float x) { return x / (1.f + __expf(-x)); }

__device__ __forceinline__ float waveRedSum(float v) {
  #pragma unroll
  for (int m = 32; m; m >>= 1) v += __shfl_xor(v, m, 64);
  return v;
}

// async global->LDS, 16 bytes per lane; lds dst must be waveBase + lane*16
__device__ __forceinline__ void gl2lds(const uint16_t* g, uint16_t* l) {
  __builtin_amdgcn_global_load_lds(
      (const __attribute__((address_space(1))) void*)g,
      (__attribute__((address_space(3))) void*)l, 16, 0, 0);
}

// ---------------- fallback when workspace too small ----------------
__global__ __launch_bounds__(256) void k_fallback(float* __restrict__ out, int n, float wsmb) {
  for (int i = blockIdx.x * 256 + threadIdx.x; i < n; i += gridDim.x * 256)
    out[i] = (i == 0) ? wsmb : 0.f;
}

// ---------------- fp32 -> bf16 conversion (weights) ----------------
__global__ __launch_bounds__(256) void k_f2bf(const float* __restrict__ src,
                                              uint16_t* __restrict__ dst, int n) {
  for (int i = blockIdx.x * 256 + threadIdx.x; i < n; i += gridDim.x * 256)
    dst[i] = f2bf(src[i]);
}

// ---------------- TimestepNorm, parallel 3-phase ----------------
__global__ __launch_bounds__(256) void k_tnsum(const float* __restrict__ x,
                                               float* __restrict__ s1g,
                                               float* __restrict__ s2g) {
  const int bg = blockIdx.x;
  const int b = bg / G_, g = bg % G_;
  const int tid = threadIdx.x;
  const int j = tid & 31;
  const int lsub = tid >> 5;
  #pragma unroll
  for (int i = 0; i < 16; ++i) {
    const int l = blockIdx.y * 128 + i * 8 + lsub;
    float v = x[((size_t)(b * L_ + l)) * D_ + g * 32 + j];
    float a = v, sq = v * v;
    #pragma unroll
    for (int m = 1; m <= 16; m <<= 1) { a += __shfl_xor(a, m, 64); sq += __shfl_xor(sq, m, 64); }
    if (j == 0) { s1g[(size_t)bg * L_ + l] = a; s2g[(size_t)bg * L_ + l] = sq; }
  }
}

__global__ __launch_bounds__(64) void k_tnscan(float* __restrict__ s1g,
                                               float* __restrict__ s2g) {
  const int bg = blockIdx.x;
  const int lane = threadIdx.x;
  #pragma unroll
  for (int pass = 0; pass < 2; ++pass) {
    float* gp = (pass ? s2g : s1g) + (size_t)bg * L_;
    float loc[32];
    const int b0 = lane * 32;
    float tot = 0.f;
    #pragma unroll
    for (int t = 0; t < 32; ++t) { loc[t] = gp[b0 + t]; tot += loc[t]; }
    float incl = tot;
    #pragma unroll
    for (int off = 1; off < 64; off <<= 1) {
      float nv = __shfl_up(incl, off, 64);
      if (lane >= off) incl += nv;
    }
    float run = incl - tot;
    #pragma unroll
    for (int t = 0; t < 32; ++t) { run += loc[t]; gp[b0 + t] = run; }
  }
}

// Writes xn AND xnT (fused transpose via 32x128 LDS tile).
// NOTE (round-10 fix): xnT must NOT alias s1g/s2g — round-9 placed xnT
// over s1g/s2g and raced other blocks' s1/s2 reads (NaN).  s1g/s2g now
// live in region D (p+132MB), xnT keeps [32,64).
__global__ __launch_bounds__(256) void k_tnnorm(const float* __restrict__ x,
                                                const float* __restrict__ s1g,
                                                const float* __restrict__ s2g,
                                                const float* __restrict__ pm,
                                                const float* __restrict__ plv,
                                                const float* __restrict__ w,
                                                const float* __restrict__ bias,
                                                uint16_t* __restrict__ xn,
                                                uint16_t* __restrict__ xnT) {
  __shared__ uint16_t xt[32 * 136];
  const int bg = blockIdx.x;
  const int b = bg / G_, g = bg % G_;
  const int tid = threadIdx.x;
  const int j = tid & 31;
  const int lsub = tid >> 5;
  const float pmv = pm[g];
  const float pvv = __expf(plv[g]);
  const float wj = w[g * 32 + j];
  const float bj = bias[g * 32 + j];
  const float pterm = PC_ * (pvv + pmv * pmv);
  #pragma unroll
  for (int i = 0; i < 16; ++i) {
    const int l = blockIdx.y * 128 + i * 8 + lsub;
    const size_t idx = ((size_t)(b * L_ + l)) * D_ + g * 32 + j;
    const float v = x[idx];
    const float cnt = PC_ + 32.f * (float)(l + 1);
    const float mean = (PC_ * pmv + s1g[(size_t)bg * L_ + l]) / cnt;
    const float var = (pterm + s2g[(size_t)bg * L_ + l]) / cnt - mean * mean;
    const uint16_t o = f2bf((v - mean) * rsqrtf(var + EPS_) * wj + bj);
    xn[idx] = o;
    xt[j * 136 + i * 8 + lsub] = o;
  }
  __syncthreads();
  const int row = tid >> 3, ch = tid & 7;
  uint16_t* dst = xnT + ((size_t)(b * D_ + g * 32 + row)) * L_ + blockIdx.y * 128 + ch * 16;
  *(bf16x8*)&dst[0] = *(const bf16x8*)&xt[row * 136 + ch * 16];
  *(bf16x8*)&dst[8] = *(const bf16x8*)&xt[row * 136 + ch * 16 + 8];
}

// ---------------- vectorized 64x64-tile f32 transpose ----------------
__global__ __launch_bounds__(256) void k_tpf32(const float* __restrict__ src,
                                               float* __restrict__ dst, int R, int C) {
  __shared__ float tile[64 * 65];
  const size_t batch = (size_t)R * C * blockIdx.z;
  const int c0 = blockIdx.x * 64, r0 = blockIdx.y * 64;
  const int t = threadIdx.x;
  const int rr = t >> 4;          // 0..15
  const int cc = (t & 15) * 4;    // 0..60
  #pragma unroll
  for (int p = 0; p < 4; ++p) {
    const int row = p * 16 + rr;
    f32x4 v = *(const f32x4*)&src[batch + (size_t)(r0 + row) * C + c0 + cc];
    #pragma unroll
    for (int i = 0; i < 4; ++i) tile[(cc + i) * 65 + row] = v[i];
  }
  __syncthreads();
  #pragma unroll
  for (int p = 0; p < 4; ++p) {
    const int crow = p * 16 + rr;
    f32x4 o;
    #pragma unroll
    for (int i = 0; i < 4; ++i) o[i] = tile[crow * 65 + cc + i];
    *(f32x4*)&dst[batch + (size_t)(c0 + crow) * R + r0 + cc] = o;
  }
}

// ---------------- MultiHeadEMA via chunked linear recurrence ----------------
__global__ __launch_bounds__(64) void k_ema(const uint16_t* __restrict__ xnT,
                                            const float* __restrict__ delta,
                                            const float* __restrict__ alpha,
                                            const float* __restrict__ beta,
                                            const float* __restrict__ gamma,
                                            const float* __restrict__ omega,
                                            float* __restrict__ mxT) {
  __shared__ float hst[64 * NE_];
  const int bd = blockIdx.x;
  const int d = bd & (D_ - 1);
  const int c = threadIdx.x;

  float q[NE_], pb[NE_], gs[NE_];
  #pragma unroll
  for (int n = 0; n < NE_; ++n) {
    float p = sigmoidf_(delta[d * NE_ + n]);
    float a = sigmoidf_(alpha[d * NE_ + n]);
    q[n] = 1.f - p * a;
    pb[n] = p * beta[d * NE_ + n];
    gs[n] = gamma[d * NE_ + n] * 0.25f;
  }

  const uint16_t* xp = xnT + (size_t)bd * L_ + c * 32;
  bf16x8 xin[4];
  #pragma unroll
  for (int s = 0; s < 4; ++s) xin[s] = *(const bf16x8*)(xp + s * 8);

  float h[NE_];
  #pragma unroll
  for (int n = 0; n < NE_; ++n) h[n] = 0.f;

  #pragma unroll
  for (int k = 0; k < 32; ++k) {
    float xv = bf2f((uint16_t)xin[k >> 3][k & 7]);
    #pragma unroll
    for (int n = 0; n < NE_; ++n) h[n] = fmaf(q[n], h[n], pb[n] * xv);
  }
  #pragma unroll
  for (int n = 0; n < NE_; ++n) hst[c * NE_ + n] = h[n];
  __syncthreads();

  if (c < NE_) {
    float qq = q[c];
    float q32 = qq * qq; q32 *= q32; q32 *= q32; q32 *= q32; q32 *= q32;  // q^32
    float hi = 0.f;
    for (int cc = 0; cc < 64; ++cc) {
      float cur = hst[cc * NE_ + c];
      hst[cc * NE_ + c] = hi;
      hi = fmaf(q32, hi, cur);
    }
  }
  __syncthreads();

  #pragma unroll
  for (int n = 0; n < NE_; ++n) h[n] = hst[c * NE_ + n];
  const float om = omega[d];
  float* op = mxT + (size_t)bd * L_ + c * 32;
  f32x4 ov;
  #pragma unroll
  for (int k = 0; k < 32; ++k) {
    float xv = bf2f((uint16_t)xin[k >> 3][k & 7]);
    float accv = 0.f;
    #pragma unroll
    for (int n = 0; n < NE_; ++n) {
      h[n] = fmaf(q[n], h[n], pb[n] * xv);
      accv = fmaf(gs[n], h[n], accv);
    }
    ov[k & 3] = accv + om * xv;
    if ((k & 3) == 3) *(f32x4*)(op + (k & ~3)) = ov;
  }
}

// ---------------- RMS norm over D ----------------
__global__ __launch_bounds__(256) void k_rms(const float* __restrict__ mx,
                                             const float* __restrict__ w,
                                             uint16_t* __restrict__ mxn) {
  __shared__ float red[4];
  const size_t row = blockIdx.x;
  const int tid = threadIdx.x;
  float ss = 0.f;
  #pragma unroll
  for (int i = 0; i < 4; ++i) {
    float v = mx[row * D_ + tid + i * 256];
    ss += v * v;
  }
  ss = waveRedSum(ss);
  if ((tid & 63) == 0) red[tid >> 6] = ss;
  __syncthreads();
  ss = red[0] + red[1] + red[2] + red[3];
  const float scale = rsqrtf(ss * (1.f / D_) + EPS_);
  #pragma unroll
  for (int i = 0; i < 4; ++i) {
    int dcol = tid + i * 256;
    mxn[row * D_ + dcol] = f2bf(mx[row * D_ + dcol] * scale * w[dcol]);
  }
}

// ==================================================================
// 128x128-tile, BK=32, 4-wave, 2-phase prefetch GEMM, 4 blocks/CU.
// (round-6/7 structure — at the 2-phase plateau, ~606 TF on BASE)
//
// MODE 1's bf16 outputs (u, r, q/k) go through an LDS-transit epilogue
// (full-cacheline 16B/lane stores).  Direct 2B scattered stores were
// 32B partial lines -> L2 read-allocate traffic.  Every 128-col tile is
// entirely one region: rt = bn>>7: 0-7 u, 8 q/k, 9-24 r, 25-32 hx
// (f32, already full lines, stays direct).
//
// C = A(MxK) @ B(NxK)^T, fused epilogues:
//  MODE 0: V     vT[b][h][l] = silu(acc + bv[h])         (transposed)
//  MODE 1: BASE  acc + bmx[col], split u/(q,k)/r/hx
//  MODE 4: WH    g=silu(acc+hx); out = x + u*(g-x)        -> f32 d_out
// ==================================================================

template <int MODE>
__global__ __launch_bounds__(256, 4) void k_gemm128(
    const uint16_t* __restrict__ A, const uint16_t* __restrict__ Bm,
    int N, int K,
    const float* __restrict__ bias,
    float* __restrict__ outf, uint16_t* __restrict__ outb,
    uint16_t* __restrict__ ubuf,
    uint16_t* __restrict__ rbuf, float* __restrict__ hxbuf,
    const float* __restrict__ x0,
    const float* __restrict__ qkg, const float* __restrict__ qkb,
    uint16_t* __restrict__ qbuf, uint16_t* __restrict__ kbuf) {
  __shared__ uint16_t sm[17408];  // 34.8 KiB: dbuf at 0/8192; epi transit reuses all
  const int t = threadIdx.x;
  const int lane = t & 63, wave = t >> 6;
  const int quad = lane >> 4, r16 = lane & 15;
  const int wm = wave >> 1, wn = wave & 1;
  const int bm = blockIdx.x * 128;
  const int bn = blockIdx.y * 128;

  f32x4 acc[4][4];
  const f32x4 zf = {0.f, 0.f, 0.f, 0.f};
  #pragma unroll
  for (int i = 0; i < 4; ++i)
    #pragma unroll
    for (int j = 0; j < 4; ++j) acc[i][j] = zf;

  // staging: thread t -> rows {t>>2, 64+(t>>2)}, phys granule t&3;
  // LDS dest linear; global col pre-swizzled: logical = (t&3)^((t>>3)&3)
  const int sgz = (((t & 3) ^ ((t >> 3) & 3)) << 3);
  const uint16_t* gA = A + (size_t)(bm + (t >> 2)) * K + sgz;
  const uint16_t* gB = Bm + (size_t)(bn + (t >> 2)) * K + sgz;
  const size_t qstep = (size_t)64 * K;
  uint16_t* lA = sm + t * 8;
  uint16_t* lB = sm + 4096 + t * 8;

  // reads: row*32 + ((quad ^ ((row>>1)&3))<<3)
  const int ga = ((quad ^ ((r16 >> 1) & 3)) << 3);
  const int aOff = (wm * 64 + r16) * 32 + ga;
  const int bOff = 4096 + (wn * 64 + r16) * 32 + ga;

#define STAGE(c, kb) do {                                                     \
    gl2lds(gA + (kb), lA + (c) * 8192);                                       \
    gl2lds(gA + qstep + (kb), lA + (c) * 8192 + 2048);                        \
    gl2lds(gB + (kb), lB + (c) * 8192);                                       \
    gl2lds(gB + qstep + (kb), lB + (c) * 8192 + 2048);                        \
  } while (0)

  const int NT = K >> 5;

  STAGE(0, 0);
  __syncthreads();  // vmcnt(0) drain + barrier

  bf16x8 af[4], bfr[4];
  for (int tt = 0; tt < NT; ++tt) {
    const int c = tt & 1;
    const int co = c * 8192;
    if (tt + 1 < NT) STAGE(c ^ 1, (tt + 1) * 32);  // prefetch next tile
    #pragma unroll
    for (int j = 0; j < 4; ++j)
      bfr[j] = *(const bf16x8*)&sm[co + bOff + j * 512];
    #pragma unroll
    for (int i = 0; i < 4; ++i)
      af[i] = *(const bf16x8*)&sm[co + aOff + i * 512];
    #pragma unroll
    for (int i = 0; i < 4; ++i)
      #pragma unroll
      for (int j = 0; j < 4; ++j)
        acc[i][j] = __builtin_amdgcn_mfma_f32_16x16x32_bf16(
            af[i], bfr[j], acc[i][j], 0, 0, 0);
    __syncthreads();  // single vmcnt(0)+barrier per K-tile
  }
#undef STAGE

  // ---- epilogue ----
  if (MODE == 0) {
    // silu+bias, store transposed into sm[h][l] (row stride 136), then
    // coalesced 16B writes to vT[b][h][l].
    #pragma unroll
    for (int i = 0; i < 4; ++i)
      #pragma unroll
      for (int j = 0; j < 4; ++j)
        #pragma unroll
        for (int r = 0; r < 4; ++r) {
          const int hloc = wn * 64 + j * 16 + r16;
          const int lloc = wm * 64 + i * 16 + quad * 4 + r;
          sm[hloc * 136 + lloc] = f2bf(siluf_(acc[i][j][r] + bias[bn + hloc]));
        }
    __syncthreads();
    const int bb = bm >> 11;            // batch index (tile never crosses)
    const int lb = bm & 2047;           // l offset within batch
    uint16_t* vTb = outb + (size_t)bb * H_ * L_;
    #pragma unroll
    for (int p = 0; p < 8; ++p) {
      const int hloc = p * 16 + (t >> 4);
      const int l0 = (t & 15) * 8;
      bf16x8 v = *(const bf16x8*)&sm[hloc * 136 + l0];
      *(bf16x8*)&vTb[(size_t)(bn + hloc) * L_ + lb + l0] = v;
    }
  } else if (MODE == 1) {
    const int rt = bn >> 7;   // 0-7 u | 8 q/k | 9-24 r | 25-32 hx
    if (rt >= 25) {
      // hx: f32 direct stores (64B full lines)
      #pragma unroll
      for (int i = 0; i < 4; ++i)
        #pragma unroll
        for (int j = 0; j < 4; ++j)
          #pragma unroll
          for (int r = 0; r < 4; ++r) {
            const int row = bm + wm * 64 + i * 16 + quad * 4 + r;
            const int col = bn + wn * 64 + j * 16 + r16;
            hxbuf[(size_t)row * D_ + (col - D_ - Z_ - H_)] = acc[i][j][r] + bias[col];
          }
    } else if (rt == 8) {
      // q/k: two LDS-transit passes (z tile = cols 1024..1151)
      #pragma unroll
      for (int pass = 0; pass < 2; ++pass) {
        #pragma unroll
        for (int i = 0; i < 4; ++i)
          #pragma unroll
          for (int j = 0; j < 4; ++j)
            #pragma unroll
            for (int r = 0; r < 4; ++r) {
              const int rowloc = wm * 64 + i * 16 + quad * 4 + r;
              const int zc = wn * 64 + j * 16 + r16;
              const float zv = siluf_(acc[i][j][r] + bias[D_ + zc]);
              const float o = pass == 0
                  ? (zv * qkg[zc] + qkb[zc]) * 0.08838834764831845f
                  : zv * qkg[Z_ + zc] + qkb[Z_ + zc];
              sm[rowloc * 136 + zc] = f2bf(o);
            }
        __syncthreads();
        uint16_t* dstb = pass == 0 ? qbuf : kbuf;
        #pragma unroll
        for (int p = 0; p < 8; ++p) {
          const int row = p * 16 + (t >> 4);
          const int c0 = (t & 15) * 8;
          bf16x8 v = *(const bf16x8*)&sm[row * 136 + c0];
          *(bf16x8*)&dstb[(size_t)(bm + row) * Z_ + c0] = v;
        }
        __syncthreads();
      }
    } else {
      // u (sigmoid) or r (silu): LDS-transit, full-line 16B stores
      const bool isU = rt < 8;
      #pragma unroll
      for (int i = 0; i < 4; ++i)
        #pragma unroll
        for (int j = 0; j < 4; ++j)
          #pragma unroll
          for (int r = 0; r < 4; ++r) {
            const int rowloc = wm * 64 + i * 16 + quad * 4 + r;
            const int colloc = wn * 64 + j * 16 + r16;
            const float val = acc[i][j][r] + bias[bn + colloc];
            sm[rowloc * 136 + colloc] = f2bf(isU ? sigmoidf_(val) : siluf_(val));
          }
      __syncthreads();
      #pragma unroll
      for (int p = 0; p < 8; ++p) {
        const int row = p * 16 + (t >> 4);
        const int c0 = (t & 15) * 8;
        bf16x8 v = *(const bf16x8*)&sm[row * 136 + c0];
        if (isU)
          *(bf16x8*)&ubuf[(size_t)(bm + row) * D_ + bn + c0] = v;
        else
          *(bf16x8*)&rbuf[(size_t)(bm + row) * H_ + (bn - D_ - Z_) + c0] = v;
      }
    }
  } else {
    #pragma unroll
    for (int i = 0; i < 4; ++i) {
      #pragma unroll
      for (int j = 0; j < 4; ++j) {
        #pragma unroll
        for (int r = 0; r < 4; ++r) {
          const int row = bm + wm * 64 + i * 16 + quad * 4 + r;
          const int col = bn + wn * 64 + j * 16 + r16;
          const size_t idx = (size_t)row * N + col;
          float g = siluf_(acc[i][j][r] + hxbuf[idx]);   // read hx (d_out) ...
          float xv = x0[idx];
          outf[idx] = xv + bf2f(ubuf[idx]) * (g - xv);  // ... then write same addr
        }
      }
    }
  }
}

// ---- fused QK^T + rel_bias + causal softmax -> packed-triangular P (bf16) ----
// K/relwin staging double-buffered with prefetch (1 barrier/kt).
__global__ __launch_bounds__(256) void k_qksm(
    const uint16_t* __restrict__ qg, const uint16_t* __restrict__ kg,
    const float* __restrict__ relb, uint16_t* __restrict__ Pp) {
  __shared__ uint16_t Ks[2 * 16384];
  __shared__ float relwin[2 * 256];
  const int qt = blockIdx.x;
  const int bl = blockIdx.y;
  const int tid = threadIdx.x;
  const int w = tid >> 6, lane = tid & 63;
  const int quad = lane >> 4, r16 = lane & 15;
  const uint16_t* qb_b = qg + (size_t)bl * L_ * Z_;
  const uint16_t* kb_b = kg + (size_t)bl * L_ * Z_;
  uint16_t* P_b = Pp + (size_t)bl * NPACK_ * TILE_ELEMS_;

  const int ksg = (tid >> 4) * 128 + (((tid & 15) ^ ((tid >> 4) & 7)) << 3);
  const int kg7 = r16 & 7;

#define STGK(c, kt) do {                                                      \
    const uint16_t* src_ = kb_b + (size_t)(kt) * 128 * Z_;                    \
    _Pragma("unroll")                                                         \
    for (int s2 = 0; s2 < 8; ++s2)                                            \
      gl2lds(src_ + s2 * 2048 + ksg, Ks + (c) * 16384 + s2 * 2048 + tid * 8); \
    if (tid < 255)                                                            \
      relwin[(c) * 256 + tid] = relb[2047 + ((kt) - qt) * 128 - 127 + tid];   \
  } while (0)

  bf16x8 aq[2][4];
  #pragma unroll
  for (int i = 0; i < 2; ++i)
    #pragma unroll
    for (int s = 0; s < 4; ++s)
      aq[i][s] = *(const bf16x8*)&qb_b[(size_t)(qt * 128 + w * 32 + i * 16 + r16) * Z_ +
                                       s * 32 + quad * 8];

  float m8[8], l8[8];
  #pragma unroll
  for (int t = 0; t < 8; ++t) { m8[t] = -3.4e38f; l8[t] = 0.f; }

  const f32x4 zf = {0.f, 0.f, 0.f, 0.f};

  // ---- phase 1: stats ----
  STGK(0, 0);
  __syncthreads();
  for (int kt = 0; kt <= qt; ++kt) {
    const int cur = kt & 1;
    if (kt < qt) STGK(cur ^ 1, kt + 1);
    const uint16_t* Kc = Ks + cur * 16384;
    const float* rw = relwin + cur * 256;
    #pragma unroll
    for (int j = 0; j < 8; ++j) {
      f32x4 a0 = zf, a1 = zf;
      #pragma unroll
      for (int s = 0; s < 4; ++s) {
        bf16x8 bk = *(const bf16x8*)&Kc[(j * 16 + r16) * 128 +
                                        (((s * 4 + quad) ^ kg7) << 3)];
        a0 = __builtin_amdgcn_mfma_f32_16x16x32_bf16(aq[0][s], bk, a0, 0, 0, 0);
        a1 = __builtin_amdgcn_mfma_f32_16x16x32_bf16(aq[1][s], bk, a1, 0, 0, 0);
      }
      #pragma unroll
      for (int i = 0; i < 2; ++i) {
        const f32x4 av = i ? a1 : a0;
        #pragma unroll
        for (int r = 0; r < 4; ++r) {
          const int rloc = w * 32 + i * 16 + quad * 4 + r;
          const int cloc = j * 16 + r16;
          if (kt < qt || cloc <= rloc) {
            const float v = av[r] + rw[cloc - rloc + 127];
            const int t = i * 4 + r;
            const float mn = fmaxf(m8[t], v);
            l8[t] = l8[t] * __expf(m8[t] - mn) + __expf(v - mn);
            m8[t] = mn;
          }
        }
      }
    }
    __syncthreads();
  }

  #pragma unroll
  for (int t = 0; t < 8; ++t) {
    #pragma unroll
    for (int msk = 1; msk <= 8; msk <<= 1) {
      const float mo = __shfl_xor(m8[t], msk, 64);
      const float lo = __shfl_xor(l8[t], msk, 64);
      const float mn = fmaxf(m8[t], mo);
      l8[t] = l8[t] * __expf(m8[t] - mn) + lo * __expf(mo - mn);
      m8[t] = mn;
    }
    l8[t] = 1.f / l8[t];
  }

  // ---- phase 2: recompute, normalize, write packed P ----
  STGK(0, 0);
  __syncthreads();
  for (int kt = 0; kt <= qt; ++kt) {
    const int cur = kt & 1;
    if (kt < qt) STGK(cur ^ 1, kt + 1);
    const uint16_t* Kc = Ks + cur * 16384;
    const float* rw = relwin + cur * 256;
    uint16_t* Pt = P_b + (size_t)(qt * (qt + 1) / 2 + kt) * TILE_ELEMS_;
    #pragma unroll
    for (int j = 0; j < 8; ++j) {
      f32x4 a0 = zf, a1 = zf;
      #pragma unroll
      for (int s = 0; s < 4; ++s) {
        bf16x8 bk = *(const bf16x8*)&Kc[(j * 16 + r16) * 128 +
                                        (((s * 4 + quad) ^ kg7) << 3)];
        a0 = __builtin_amdgcn_mfma_f32_16x16x32_bf16(aq[0][s], bk, a0, 0, 0, 0);
        a1 = __builtin_amdgcn_mfma_f32_16x16x32_bf16(aq[1][s], bk, a1, 0, 0, 0);
      }
      #pragma unroll
      for (int i = 0; i < 2; ++i) {
        const f32x4 av = i ? a1 : a0;
        #pragma unroll
        for (int r = 0; r < 4; ++r) {
          const int rloc = w * 32 + i * 16 + quad * 4 + r;
          const int cloc = j * 16 + r16;
          const int t = i * 4 + r;
          float p = 0.f;
          if (kt < qt || cloc <= rloc) {
            const float v = av[r] + rw[cloc - rloc + 127];
            p = __expf(v - m8[t]) * l8[t];
          }
          Pt[rloc * 128 + cloc] = f2bf(p);
        }
      }
    }
    __syncthreads();
  }
#undef STGK
}

// ---- PV GEMM: hr = (P @ V) * r, packed-triangular P, in-place over r ----
// 128x256 tile, 8 waves, BK=32 dbuf prefetch, 48 KiB LDS, (512,4).
__global__ __launch_bounds__(512, 4) void k_pv(
    const uint16_t* __restrict__ Pp, const uint16_t* __restrict__ vT,
    uint16_t* __restrict__ rh) {
  __shared__ uint16_t sm[24576];  // 48 KiB: buf c at c*12288; A(4096) +0, B(8192) +4096
  const int qt = NTILE_ - 1 - blockIdx.x;   // heavy blocks first
  const int bn = blockIdx.y * 256;
  const int bl = blockIdx.z;
  const uint16_t* Pq = Pp + (size_t)bl * NPACK_ * TILE_ELEMS_ +
                       (size_t)(qt * (qt + 1) / 2) * TILE_ELEMS_;
  const uint16_t* v_b = vT + (size_t)bl * H_ * L_;
  uint16_t* rh_b = rh + (size_t)bl * L_ * H_;

  const int tid = threadIdx.x;
  const int wave = tid >> 6, lane = tid & 63;
  const int quad = lane >> 4, r16 = lane & 15;
  const int wm = wave >> 2, wn = wave & 3;
  const int rowW = wm * 64, colW = wn * 64;

  f32x4 acc[4][4];
  const f32x4 zf = {0.f, 0.f, 0.f, 0.f};
  #pragma unroll
  for (int i = 0; i < 4; ++i)
    #pragma unroll
    for (int j = 0; j < 4; ++j) acc[i][j] = zf;

  const int rA = tid >> 2;   // 0..127
  const int sg = (((tid & 3) ^ ((tid >> 3) & 3)) << 3);
  const int gpv = ((quad ^ ((r16 >> 1) & 3)) << 3);

#define PVSTAGE(c, s) do {                                                    \
    const int kt_ = (s) >> 2, ks_ = (s) & 3;                                  \
    gl2lds(Pq + (size_t)kt_ * TILE_ELEMS_ + rA * 128 + ks_ * 32 + sg,         \
           sm + (c) * 12288 + tid * 8);                                       \
    const uint16_t* Bt_ = v_b + (size_t)(bn + rA) * L_ + kt_ * 128 +          \
                          ks_ * 32 + sg;                                      \
    gl2lds(Bt_, sm + (c) * 12288 + 4096 + tid * 8);                           \
    gl2lds(Bt_ + (size_t)128 * L_, sm + (c) * 12288 + 8192 + tid * 8);        \
  } while (0)

  const int S = 4 * (qt + 1);

  PVSTAGE(0, 0);
  __syncthreads();

  bf16x8 af[4], bfr[4];
  for (int s = 0; s < S; ++s) {
    const int c = s & 1;
    const int co = c * 12288;
    if (s + 1 < S) PVSTAGE(c ^ 1, s + 1);
    #pragma unroll
    for (int j = 0; j < 4; ++j)
      bfr[j] = *(const bf16x8*)&sm[co + 4096 + (colW + j * 16 + r16) * 32 + gpv];
    #pragma unroll
    for (int i = 0; i < 4; ++i)
      af[i] = *(const bf16x8*)&sm[co + (rowW + i * 16 + r16) * 32 + gpv];
    #pragma unroll
    for (int i = 0; i < 4; ++i)
      #pragma unroll
      for (int j = 0; j < 4; ++j)
        acc[i][j] = __builtin_amdgcn_mfma_f32_16x16x32_bf16(af[i], bfr[j], acc[i][j], 0, 0, 0);
    __syncthreads();
  }
#undef PVSTAGE

  #pragma unroll
  for (int i = 0; i < 4; ++i) {
    #pragma unroll
    for (int j = 0; j < 4; ++j) {
      #pragma unroll
      for (int r = 0; r < 4; ++r) {
        const int row = qt * 128 + rowW + i * 16 + quad * 4 + r;
        const int col = bn + colW + j * 16 + r16;
        const size_t idx = (size_t)row * H_ + col;
        const float rv = bf2f(rh_b[idx]);
        rh_b[idx] = f2bf(acc[i][j][r] * rv);
      }
    }
  }
}

extern "C" void kernel_launch(void* const* d_in, const int* in_sizes, int n_in,
                              void* d_out, int out_size, void* d_ws, size_t ws_size,
                              hipStream_t stream) {
  (void)in_sizes; (void)n_in;
  const float* x         = (const float*)d_in[0];
  const float* prior_mean= (const float*)d_in[1];
  const float* prior_logv= (const float*)d_in[2];
  const float* tn_w      = (const float*)d_in[3];
  const float* tn_b      = (const float*)d_in[4];
  const float* delta     = (const float*)d_in[5];
  const float* alpha     = (const float*)d_in[6];
  const float* ema_beta  = (const float*)d_in[7];
  const float* ema_gamma = (const float*)d_in[8];
  const float* omega     = (const float*)d_in[9];
  const float* rms_w     = (const float*)d_in[10];
  const float* Wv        = (const float*)d_in[11];
  const float* bv        = (const float*)d_in[12];
  const float* Wmx       = (const float*)d_in[13];
  const float* bmx       = (const float*)d_in[14];
  const float* Wh        = (const float*)d_in[15];
  const float* qk_gamma  = (const float*)d_in[16];
  const float* qk_beta   = (const float*)d_in[17];
  const float* rel_bias  = (const float*)d_in[18];
  float* out = (float*)d_out;

  const int BL = B_ * L_;
  const size_t MB = 1024 * 1024;
  const size_t REQUIRED = 256 * MB;

  if (ws_size < REQUIRED) {
    k_fallback<<<dim3(4096), dim3(256), 0, stream>>>(out, out_size, (float)(ws_size / MB));
    return;
  }

  char* p = (char*)d_ws;
  // A [0,32): xn (bf16) -> ubuf (bf16)
  uint16_t* xn   = (uint16_t*)(p);
  uint16_t* ubuf = (uint16_t*)(p);
  // B [32,64): xnT (live steps 2-4) -> mxn (live 6-7)
  uint16_t* xnT  = (uint16_t*)(p + 32 * MB);
  uint16_t* mxn  = (uint16_t*)(p + 32 * MB);
  // C [64,128): vT (64 MiB exactly; written by V GEMM, read by k_pv)
  uint16_t* vT   = (uint16_t*)(p + 64 * MB);
  // D [128,192): wv_b [128,132) steps 1-3 | s1g/s2g [132,136) step 2 only
  //              -> mx f32 (5-6) -> rbuf/hr (7-11)
  uint16_t* wv_b = (uint16_t*)(p + 128 * MB);
  float*    s1g  = (float*)   (p + 132 * MB);
  float*    s2g  = (float*)   (p + 134 * MB);
  float*    mx   = (float*)   (p + 128 * MB);
  uint16_t* rbuf = (uint16_t*)(p + 128 * MB);
  // E [192,256): wmx_b(8.25) | qb(4) | kb(4) | Ppack(35.65)
  uint16_t* wmx_b = (uint16_t*)(p + 192 * MB);
  uint16_t* wh_b  = (uint16_t*)(p + 192 * MB);
  uint16_t* qb    = (uint16_t*)(p + 209 * MB);
  uint16_t* kb2   = (uint16_t*)(p + 213 * MB);
  uint16_t* Ppack = (uint16_t*)(p + 217 * MB);
  // d_out doubles as: mxT f32 (EMA out) -> hx f32 (BASE out) -> out
  float* mxT = out;
  float* hx  = out;

  // 1. weights -> bf16
  k_f2bf<<<dim3(1024), dim3(256), 0, stream>>>(Wv, wv_b, H_ * D_);
  k_f2bf<<<dim3(2048), dim3(256), 0, stream>>>(Wmx, wmx_b, NMX_ * D_);
  // 2. timestep norm (3-phase parallel) -> xn AND xnT (fused transpose)
  k_tnsum<<<dim3(B_ * G_, 16), dim3(256), 0, stream>>>(x, s1g, s2g);
  k_tnscan<<<dim3(B_ * G_), dim3(64), 0, stream>>>(s1g, s2g);
  k_tnnorm<<<dim3(B_ * G_, 16), dim3(256), 0, stream>>>(
      x, s1g, s2g, prior_mean, prior_logv, tn_w, tn_b, xn, xnT);
  // 3. v = silu(xn @ Wv^T + bv), written TRANSPOSED -> vT (C)
  k_gemm128<0><<<dim3(BL / 128, H_ / 128), dim3(256), 0, stream>>>(
      xn, wv_b, H_, D_, bv, nullptr, vT,
      nullptr, nullptr, nullptr, nullptr, nullptr, nullptr, nullptr, nullptr);
  // 4. EMA: xnT -> mxT (d_out)
  k_ema<<<dim3(B_ * D_), dim3(64), 0, stream>>>(xnT, delta, alpha, ema_beta, ema_gamma, omega, mxT);
  // 5. mxT -> mx (vectorized f32 transpose; overwrites dead wv_b/s1s2)
  k_tpf32<<<dim3(L_ / 64, D_ / 64, B_), dim3(256), 0, stream>>>(mxT, mx, D_, L_);
  // 6. RMS norm -> mxn (overwrites dead xnT)
  k_rms<<<dim3(BL), dim3(256), 0, stream>>>(mx, rms_w, mxn);
  // 7. BASE GEMM -> u(A), q/k(E, fused qkprep), r(D), hx(d_out)
  k_gemm128<1><<<dim3(BL / 128, NMX_ / 128), dim3(256), 0, stream>>>(
      mxn, wmx_b, NMX_, D_, bmx, nullptr, nullptr,
      ubuf, rbuf, hx, nullptr, qk_gamma, qk_beta, qb, kb2);
  // 8. fused QK+softmax -> packed P (all 8 batches, one dispatch)
  k_qksm<<<dim3(NTILE_, B_), dim3(256), 0, stream>>>(qb, kb2, rel_bias, Ppack);
  // 9. PV GEMM, hr = (P@V)*r in-place over rbuf (one dispatch)
  k_pv<<<dim3(NTILE_, H_ / 256, B_), dim3(512), 0, stream>>>(Ppack, vT, rbuf);
  // 10. Wh -> bf16 (over dead wmx_b)
  k_f2bf<<<dim3(1024), dim3(256), 0, stream>>>(Wh, wh_b, D_ * H_);
  // 11. final: g = silu(hx + hr@Wh^T); out = x + u*(g-x)
  k_gemm128<4><<<dim3(BL / 128, D_ / 128), dim3(256), 0, stream>>>(
      rbuf, wh_b, D_, H_, nullptr, out, nullptr,
      ubuf, nullptr, hx, x, nullptr, nullptr, nullptr, nullptr);
}